// Round 7
// baseline (1183.949 us; speedup 1.0000x reference)
//
#include <hip/hip_runtime.h>
#include <math.h>

#define NB 128            // graphs
#define NN 1024           // nodes per graph
#define BNODES (NB*NN)    // 131072
#define NE 2097152        // edges
#define FH 64             // hidden
#define KK1 820
#define KK2 656
#define KK3 525

// ---------------- CSR build ----------------
__global__ void k_init(int* __restrict__ cnt, int* __restrict__ aliveA, float* __restrict__ g) {
  int i = blockIdx.x*256 + threadIdx.x;
  if (i < BNODES) { cnt[i] = 0; aliveA[i] = 1; }
  if (i < NB*2*FH) g[i] = 0.f;
}

__global__ void k_count(const int* __restrict__ ei, int* __restrict__ cnt) {
  int e = blockIdx.x*256 + threadIdx.x;
  if (e < NE) atomicAdd(&cnt[ei[NE + e]], 1);
}

// hierarchical scan: 512-block partial sums -> scan partials -> apply
__global__ void k_scan1(const int* __restrict__ cnt, int* __restrict__ part) {
  __shared__ int ps[256];
  int t = threadIdx.x;
  ps[t] = cnt[blockIdx.x*256 + t];
  __syncthreads();
  for (int off = 128; off > 0; off >>= 1) {
    if (t < off) ps[t] += ps[t + off];
    __syncthreads();
  }
  if (t == 0) part[blockIdx.x] = ps[0];
}

__global__ void k_scan2(const int* __restrict__ part, int* __restrict__ poff) {
  __shared__ int ps[512];
  int t = threadIdx.x;
  int v = part[t];
  ps[t] = v;
  __syncthreads();
  for (int off = 1; off < 512; off <<= 1) {
    int u = (t >= off) ? ps[t - off] : 0;
    __syncthreads();
    ps[t] += u;
    __syncthreads();
  }
  poff[t] = ps[t] - v;   // exclusive
}

__global__ void k_scan3(const int* __restrict__ cnt, const int* __restrict__ poff,
                        int* __restrict__ rowptr, int* __restrict__ cursor) {
  __shared__ int ps[256];
  int t = threadIdx.x, i = blockIdx.x*256 + t;
  int v = cnt[i];
  ps[t] = v;
  __syncthreads();
  for (int off = 1; off < 256; off <<= 1) {
    int u = (t >= off) ? ps[t - off] : 0;
    __syncthreads();
    ps[t] += u;
    __syncthreads();
  }
  int r = poff[blockIdx.x] + ps[t] - v;
  rowptr[i] = r;
  cursor[i] = r;
  if (i == BNODES - 1) rowptr[BNODES] = NE;
}

// packed payload {src, bits(w)} in CSR order
__global__ void k_fill(const int* __restrict__ ei, const float* __restrict__ ea,
                       int* __restrict__ cursor, int2* __restrict__ csr_sw) {
  int e = blockIdx.x*256 + threadIdx.x;
  if (e >= NE) return;
  int s = ei[e], d = ei[NE + e];
  int pos = atomicAdd(&cursor[d], 1);
  csr_sw[pos] = make_int2(s, __float_as_int(ea[e]));
}

// ---------------- fused degrees + linear transform ----------------
// blocks [0,512): per-node degree pass -> dinvW/dinvU (0 for dead nodes)
// blocks [512, grid): linear transform (lin1 for layer1, lin64 otherwise)
// MODE 0: w=ea, all alive | MODE 1: w=ea*mask | MODE 2: w=mask
template<int MODE, bool L1>
__global__ void k_degs_lin(const int* __restrict__ rowptr, const int2* __restrict__ csr_sw,
                           const int* __restrict__ alive,
                           float* __restrict__ dinvW, float* __restrict__ dinvU,
                           const float* __restrict__ xin, const float* __restrict__ W,
                           float* __restrict__ hB) {
  if (blockIdx.x < 512) {
    int d = blockIdx.x*256 + threadIdx.x;
    int r0 = rowptr[d], r1 = rowptr[d+1];
    float sW = 0.f, sU = 0.f;
    bool dA = (MODE == 0) || (alive[d] != 0);
    if (dA) {
      if (MODE == 0) {
        sU = (float)(r1 - r0);
        for (int j = r0; j < r1; ++j) sW += __int_as_float(csr_sw[j].y);
      } else {
        for (int j = r0; j < r1; ++j) {
          int2 p = csr_sw[j];
          if (alive[p.x]) { sW += (MODE == 2) ? 1.f : __int_as_float(p.y); sU += 1.f; }
        }
      }
      dinvW[d] = rsqrtf(1.f + sW);
      dinvU[d] = rsqrtf(1.f + sU);
    } else {
      dinvW[d] = 0.f;          // dead-node encoding: coefficients self-mask
      dinvU[d] = 0.f;
    }
    return;
  }
  // ----- linear part -----
  if (L1) {
    int nblk = gridDim.x - 512;
    for (int u = (blockIdx.x - 512)*256 + threadIdx.x; u < BNODES*FH; u += nblk*256) {
      int node = u >> 6, f = u & 63;
      hB[u] = xin[2*node]*W[f] + xin[2*node+1]*W[FH + f];
    }
  } else {
    __shared__ float sW[FH*FH];
    int t = threadIdx.x;
    for (int i = t; i < FH*FH; i += 256) sW[i] = W[i];
    __syncthreads();
    int r = t >> 6, f = t & 63;
    int nblk = gridDim.x - 512;
    for (int g0 = blockIdx.x - 512; g0 < BNODES/4; g0 += nblk) {
      int node = g0*4 + r;
      const float* xr = xin + (size_t)node*FH;
      float acc = 0.f;
      #pragma unroll
      for (int k = 0; k < FH; ++k) acc = fmaf(xr[k], sW[k*FH + f], acc);
      hB[(size_t)node*FH + f] = acc;
    }
  }
}

// ---------------- fused GCN gather (4 nodes/wave, float4/lane) ----------------
// 16-lane group per dst node; lane l16 holds features 4*l16..4*l16+3.
// dead nodes have dinv==0 -> coefficients vanish, no alive[] loads needed.
template<int MODE>
__global__ void k_gather(const int* __restrict__ rowptr, const int2* __restrict__ csr_sw,
                         const float* __restrict__ dinvW, const float* __restrict__ dinvU,
                         const float* __restrict__ hB, const float* __restrict__ b,
                         const float* __restrict__ Wp,
                         float* __restrict__ hA, float* __restrict__ q) {
  int cpx = gridDim.x >> 3;
  int blk = (blockIdx.x & 7) * cpx + (blockIdx.x >> 3);   // XCD swizzle (grid%8==0)
  int t = threadIdx.x;
  int l16 = t & 15;
  int d = blk*16 + (t >> 4);                               // 16 nodes per 256-thread block
  const float4* hB4 = (const float4*)hB;

  float dd = dinvW[d];
  float4 hv = hB4[(size_t)d*16 + l16];
  float4 bv = ((const float4*)b)[l16];
  float dd2 = dd*dd;
  float4 acc;
  acc.x = fmaf(dd2, hv.x, bv.x);
  acc.y = fmaf(dd2, hv.y, bv.y);
  acc.z = fmaf(dd2, hv.z, bv.z);
  acc.w = fmaf(dd2, hv.w, bv.w);

  int r0 = rowptr[d], r1 = rowptr[d+1];
  for (int base = r0; base < r1; base += 16) {
    int m = r1 - base;
    int sj = 0; float cj = 0.f;
    if (l16 < m) {
      int2 p = csr_sw[base + l16];
      sj = p.x;
      float w = (MODE == 2) ? 1.f : __int_as_float(p.y);
      cj = dinvW[sj] * w * dd;      // 0 if src or dst dead
    }
    #pragma unroll
    for (int j = 0; j < 16; ++j) {
      int s   = __shfl(sj, j, 16);
      float c = __shfl(cj, j, 16);
      if (c != 0.f) {
        float4 v = hB4[(size_t)s*16 + l16];
        acc.x = fmaf(c, v.x, acc.x);
        acc.y = fmaf(c, v.y, acc.y);
        acc.z = fmaf(c, v.z, acc.z);
        acc.w = fmaf(c, v.w, acc.w);
      }
    }
  }
  acc.x = fmaxf(acc.x, 0.f); acc.y = fmaxf(acc.y, 0.f);
  acc.z = fmaxf(acc.z, 0.f); acc.w = fmaxf(acc.w, 0.f);
  ((float4*)hA)[(size_t)d*16 + l16] = acc;

  float4 wp = ((const float4*)Wp)[l16];
  float dot = acc.x*wp.x + acc.y*wp.y + acc.z*wp.z + acc.w*wp.w;
  #pragma unroll
  for (int off = 8; off; off >>= 1) dot += __shfl_xor(dot, off, 16);
  if (l16 == 0) q[d] = dinvU[d] * dot;    // q = dinvU * (h . Wp); 0 at dead nodes
}

// ---------------- fused score + top-k + pool-scale + readout ----------------
// one 1024-thread block per graph; scores from LDS-staged q.
__global__ __launch_bounds__(1024) void k_stk(
    const int* __restrict__ rowptr, const int2* __restrict__ csr_sw,
    const int* __restrict__ alive, const float* __restrict__ dinvU,
    const float* __restrict__ q, const float* __restrict__ bp,
    int k, float kf, float* __restrict__ h,
    int* __restrict__ aliveNext, float* __restrict__ g) {
  __shared__ float sq[NN];
  __shared__ float sc[NN];
  __shared__ float tm[NN];
  __shared__ float red1[16][FH];
  __shared__ float red2[16][FH];
  int b = blockIdx.x, t = threadIdx.x;
  int node = b*NN + t;
  sq[t] = q[node];
  __syncthreads();
  float du = dinvU[node];
  float sum = sq[t];                        // self: du*q[d] = du^2*sse
  int r0 = rowptr[node], r1 = rowptr[node+1];
  for (int j = r0; j < r1; ++j) sum += sq[csr_sw[j].x - b*NN];
  float raw = bp[0] + du*sum;               // dead: du=0 -> bp (masked below)
  int alv = alive[node];
  float me = alv ? raw : -INFINITY;
  sc[t] = me;
  __syncthreads();
  int rank = 0;
  const float4* sc4 = (const float4*)sc;
  for (int j4 = 0; j4 < NN/4; ++j4) {
    float4 o = sc4[j4];
    int jb = j4*4;
    rank += (o.x > me) || (o.x == me && jb+0 < t);
    rank += (o.y > me) || (o.y == me && jb+1 < t);
    rank += (o.z > me) || (o.z == me && jb+2 < t);
    rank += (o.w > me) || (o.w == me && jb+3 < t);
  }
  int sel = (rank < k) ? 1 : 0;
  aliveNext[node] = sel;
  __syncthreads();                          // everyone done reading sc
  tm[t] = sel ? tanhf(raw) : 0.f;
  sc[t] = sel ? 1.f : 0.f;
  __syncthreads();
  int f = t & 63, r = t >> 6;               // wave r handles nodes r, r+16, ...
  float mx = -INFINITY, sm = 0.f;
  float* hb = h + (size_t)b*NN*FH;
  for (int kk = 0; kk < 64; ++kk) {
    int n = r + kk*16;
    float tv = tm[n];
    size_t idx = (size_t)n*FH + f;
    float v = hb[idx] * tv;
    hb[idx] = v;
    if (sc[n] != 0.f) { mx = fmaxf(mx, v); sm += v; }
  }
  red1[r][f] = mx; red2[r][f] = sm;
  __syncthreads();
  if (t < FH) {
    float m2 = -INFINITY, s2 = 0.f;
    #pragma unroll
    for (int rr = 0; rr < 16; ++rr) { m2 = fmaxf(m2, red1[rr][t]); s2 += red2[rr][t]; }
    g[b*2*FH + t] += m2;
    g[b*2*FH + FH + t] += s2 / kf;
  }
}

// ---------------- MLP head + log_softmax ----------------
__global__ void k_mlp(const float* __restrict__ g,
                      const float* __restrict__ Wl1, const float* __restrict__ bl1,
                      const float* __restrict__ Wl2, const float* __restrict__ bl2,
                      const float* __restrict__ Wl3, const float* __restrict__ bl3,
                      float* __restrict__ out) {
  __shared__ float sg[2*FH];
  __shared__ float l1[FH];
  __shared__ float l2[FH/2];
  __shared__ float l3[2];
  int b = blockIdx.x, t = threadIdx.x;
  sg[t] = g[b*2*FH + t];
  sg[FH + t] = g[b*2*FH + FH + t];
  __syncthreads();
  float acc = bl1[t];
  #pragma unroll
  for (int k = 0; k < 2*FH; ++k) acc = fmaf(sg[k], Wl1[k*FH + t], acc);
  l1[t] = fmaxf(acc, 0.f);
  __syncthreads();
  if (t < 32) {
    float a2 = bl2[t];
    #pragma unroll
    for (int k = 0; k < FH; ++k) a2 = fmaf(l1[k], Wl2[k*32 + t], a2);
    l2[t] = fmaxf(a2, 0.f);
  }
  __syncthreads();
  if (t < 2) {
    float a3 = bl3[t];
    #pragma unroll
    for (int k = 0; k < 32; ++k) a3 = fmaf(l2[k], Wl3[k*2 + t], a3);
    l3[t] = a3;
  }
  __syncthreads();
  if (t == 0) {
    float m = fmaxf(l3[0], l3[1]);
    float lse = m + logf(expf(l3[0]-m) + expf(l3[1]-m));
    out[b*2+0] = l3[0] - lse;
    out[b*2+1] = l3[1] - lse;
  }
}

extern "C" void kernel_launch(void* const* d_in, const int* in_sizes, int n_in,
                              void* d_out, int out_size, void* d_ws, size_t ws_size,
                              hipStream_t stream) {
  const float* x   = (const float*)d_in[0];
  const float* ea  = (const float*)d_in[1];
  const float* W1  = (const float*)d_in[2];
  const float* b1  = (const float*)d_in[3];
  const float* Wp1 = (const float*)d_in[4];
  const float* bp1 = (const float*)d_in[5];
  const float* W2  = (const float*)d_in[6];
  const float* b2  = (const float*)d_in[7];
  const float* Wp2 = (const float*)d_in[8];
  const float* bp2 = (const float*)d_in[9];
  const float* W3  = (const float*)d_in[10];
  const float* b3  = (const float*)d_in[11];
  const float* Wp3 = (const float*)d_in[12];
  const float* bp3 = (const float*)d_in[13];
  const float* Wl1 = (const float*)d_in[14];
  const float* bl1 = (const float*)d_in[15];
  const float* Wl2 = (const float*)d_in[16];
  const float* bl2 = (const float*)d_in[17];
  const float* Wl3 = (const float*)d_in[18];
  const float* bl3 = (const float*)d_in[19];
  const int*   ei  = (const int*)d_in[20];
  float* out = (float*)d_out;

  float* hA    = (float*)d_ws;                       // BNODES*FH
  float* hB    = hA + (size_t)BNODES*FH;             // BNODES*FH
  float* dinvW = hB + (size_t)BNODES*FH;             // BNODES
  float* dinvU = dinvW + BNODES;                     // BNODES
  float* q     = dinvU + BNODES;                     // BNODES
  float* g     = q + BNODES;                         // NB*2*FH
  int* aliveA  = (int*)(g + NB*2*FH);                // BNODES
  int* aliveB  = aliveA + BNODES;                    // BNODES
  int* cnt     = aliveB + BNODES;                    // BNODES
  int* rowptr  = cnt + BNODES;                       // BNODES+1
  int* cursor  = rowptr + BNODES + 1;                // BNODES
  int* part    = cursor + BNODES;                    // 512
  int* poff    = part + 512;                         // 512
  int2* csr_sw = (int2*)(poff + 512 + 2);            // NE (8B aligned)

  const int TB = 256;
  const int gE  = NE / TB;
  const int gN  = BNODES / TB;         // 512
  const int gG  = BNODES / 16;         // 8192 gather blocks
  const int gDL = 4096;                // 512 degs + 3584 lin blocks

  // CSR build
  k_init<<<gN, TB, 0, stream>>>(cnt, aliveA, g);
  k_count<<<gE, TB, 0, stream>>>(ei, cnt);
  k_scan1<<<512, 256, 0, stream>>>(cnt, part);
  k_scan2<<<1, 512, 0, stream>>>(part, poff);
  k_scan3<<<512, 256, 0, stream>>>(cnt, poff, rowptr, cursor);
  k_fill<<<gE, TB, 0, stream>>>(ei, ea, cursor, csr_sw);

  // ===== Layer 1 =====
  k_degs_lin<0,true><<<gDL, TB, 0, stream>>>(rowptr, csr_sw, aliveA, dinvW, dinvU, x, W1, hB);
  k_gather<0><<<gG, TB, 0, stream>>>(rowptr, csr_sw, dinvW, dinvU, hB, b1, Wp1, hA, q);
  k_stk<<<NB, NN, 0, stream>>>(rowptr, csr_sw, aliveA, dinvU, q, bp1, KK1, (float)KK1, hA, aliveB, g);

  // ===== Layer 2 =====
  k_degs_lin<1,false><<<gDL, TB, 0, stream>>>(rowptr, csr_sw, aliveB, dinvW, dinvU, hA, W2, hB);
  k_gather<1><<<gG, TB, 0, stream>>>(rowptr, csr_sw, dinvW, dinvU, hB, b2, Wp2, hA, q);
  k_stk<<<NB, NN, 0, stream>>>(rowptr, csr_sw, aliveB, dinvU, q, bp2, KK2, (float)KK2, hA, aliveA, g);

  // ===== Layer 3 =====
  k_degs_lin<2,false><<<gDL, TB, 0, stream>>>(rowptr, csr_sw, aliveA, dinvW, dinvU, hA, W3, hB);
  k_gather<2><<<gG, TB, 0, stream>>>(rowptr, csr_sw, dinvW, dinvU, hB, b3, Wp3, hA, q);
  k_stk<<<NB, NN, 0, stream>>>(rowptr, csr_sw, aliveA, dinvU, q, bp3, KK3, (float)KK3, hA, aliveB, g);

  k_mlp<<<NB, FH, 0, stream>>>(g, Wl1, bl1, Wl2, bl2, Wl3, bl3, out);
}

// Round 8
// 651.831 us; speedup vs baseline: 1.8163x; 1.8163x over previous
//
#include <hip/hip_runtime.h>
#include <math.h>

#define NB 128            // graphs
#define NN 1024           // nodes per graph
#define BNODES (NB*NN)    // 131072
#define NE 2097152        // edges
#define FH 64             // hidden
#define KK1 820
#define KK2 656
#define KK3 525

// ---------------- CSR build ----------------
__global__ void k_init(int* __restrict__ cnt, int* __restrict__ aliveA, float* __restrict__ g) {
  int i = blockIdx.x*256 + threadIdx.x;
  if (i < BNODES) { cnt[i] = 0; aliveA[i] = 1; }
  if (i < NB*2*FH) g[i] = 0.f;
}

__global__ void k_count(const int* __restrict__ ei, int* __restrict__ cnt) {
  int e = blockIdx.x*256 + threadIdx.x;
  if (e < NE) atomicAdd(&cnt[ei[NE + e]], 1);
}

// hierarchical scan: 512-block partial sums -> scan partials -> apply
__global__ void k_scan1(const int* __restrict__ cnt, int* __restrict__ part) {
  __shared__ int ps[256];
  int t = threadIdx.x;
  ps[t] = cnt[blockIdx.x*256 + t];
  __syncthreads();
  for (int off = 128; off > 0; off >>= 1) {
    if (t < off) ps[t] += ps[t + off];
    __syncthreads();
  }
  if (t == 0) part[blockIdx.x] = ps[0];
}

__global__ void k_scan2(const int* __restrict__ part, int* __restrict__ poff) {
  __shared__ int ps[512];
  int t = threadIdx.x;
  int v = part[t];
  ps[t] = v;
  __syncthreads();
  for (int off = 1; off < 512; off <<= 1) {
    int u = (t >= off) ? ps[t - off] : 0;
    __syncthreads();
    ps[t] += u;
    __syncthreads();
  }
  poff[t] = ps[t] - v;   // exclusive
}

__global__ void k_scan3(const int* __restrict__ cnt, const int* __restrict__ poff,
                        int* __restrict__ rowptr, int* __restrict__ cursor) {
  __shared__ int ps[256];
  int t = threadIdx.x, i = blockIdx.x*256 + t;
  int v = cnt[i];
  ps[t] = v;
  __syncthreads();
  for (int off = 1; off < 256; off <<= 1) {
    int u = (t >= off) ? ps[t - off] : 0;
    __syncthreads();
    ps[t] += u;
    __syncthreads();
  }
  int r = poff[blockIdx.x] + ps[t] - v;
  rowptr[i] = r;
  cursor[i] = r;
  if (i == BNODES - 1) rowptr[BNODES] = NE;
}

// packed payload {src, bits(w)} in CSR order
__global__ void k_fill(const int* __restrict__ ei, const float* __restrict__ ea,
                       int* __restrict__ cursor, int2* __restrict__ csr_sw) {
  int e = blockIdx.x*256 + threadIdx.x;
  if (e >= NE) return;
  int s = ei[e], d = ei[NE + e];
  int pos = atomicAdd(&cursor[d], 1);
  csr_sw[pos] = make_int2(s, __float_as_int(ea[e]));
}

// ---------------- degrees: 16-lane group per node, coalesced edge reads ----------------
// MODE 0: w=ea, all alive | MODE 1: w=ea*mask | MODE 2: w=mask
// dead nodes get dinv=0 -> downstream coefficients self-mask.
template<int MODE>
__global__ void k_degs(const int* __restrict__ rowptr, const int2* __restrict__ csr_sw,
                       const int* __restrict__ alive,
                       float* __restrict__ dinvW, float* __restrict__ dinvU) {
  int t = threadIdx.x;
  int l16 = t & 15;
  int d = blockIdx.x*16 + (t >> 4);
  int r0 = rowptr[d], r1 = rowptr[d+1];
  float sW = 0.f, sU = 0.f;
  for (int base = r0; base < r1; base += 16) {
    if (base + l16 < r1) {
      int2 p = csr_sw[base + l16];
      bool ok = (MODE == 0) || (alive[p.x] != 0);
      if (ok) { sW += (MODE == 2) ? 1.f : __int_as_float(p.y); sU += 1.f; }
    }
  }
  #pragma unroll
  for (int off = 8; off; off >>= 1) {
    sW += __shfl_xor(sW, off, 16);
    sU += __shfl_xor(sU, off, 16);
  }
  if (l16 == 0) {
    bool dA = (MODE == 0) || (alive[d] != 0);
    dinvW[d] = dA ? rsqrtf(1.f + sW) : 0.f;
    dinvU[d] = dA ? rsqrtf(1.f + sU) : 0.f;
  }
}

// ---------------- feature transforms ----------------
__global__ void k_lin1(const float* __restrict__ x, const float* __restrict__ W,
                       float* __restrict__ h) {
  int i = blockIdx.x*256 + threadIdx.x;
  if (i >= BNODES*FH) return;
  int node = i >> 6, f = i & 63;
  h[i] = x[2*node]*W[f] + x[2*node+1]*W[FH + f];
}

__global__ void k_lin64(const float* __restrict__ xin, const float* __restrict__ W,
                        float* __restrict__ out) {
  __shared__ float sW[FH*FH];
  int t = threadIdx.x;
  for (int i = t; i < FH*FH; i += 256) sW[i] = W[i];
  __syncthreads();
  int r = t >> 6, f = t & 63;
  for (int g0 = blockIdx.x; g0 < BNODES/4; g0 += gridDim.x) {
    int node = g0*4 + r;
    const float* xr = xin + (size_t)node*FH;
    float acc = 0.f;
    #pragma unroll
    for (int k = 0; k < FH; ++k) acc = fmaf(xr[k], sW[k*FH + f], acc);
    out[(size_t)node*FH + f] = acc;
  }
}

// ---------------- fused GCN gather (4 nodes/wave, float4/lane) ----------------
template<int MODE>
__global__ void k_gather(const int* __restrict__ rowptr, const int2* __restrict__ csr_sw,
                         const float* __restrict__ dinvW, const float* __restrict__ dinvU,
                         const float* __restrict__ hB, const float* __restrict__ b,
                         const float* __restrict__ Wp,
                         float* __restrict__ hA, float* __restrict__ q) {
  int cpx = gridDim.x >> 3;
  int blk = (blockIdx.x & 7) * cpx + (blockIdx.x >> 3);   // XCD swizzle (grid%8==0)
  int t = threadIdx.x;
  int l16 = t & 15;
  int d = blk*16 + (t >> 4);                               // 16 nodes per 256-thread block
  const float4* hB4 = (const float4*)hB;

  float dd = dinvW[d];
  float4 hv = hB4[(size_t)d*16 + l16];
  float4 bv = ((const float4*)b)[l16];
  float dd2 = dd*dd;
  float4 acc;
  acc.x = fmaf(dd2, hv.x, bv.x);
  acc.y = fmaf(dd2, hv.y, bv.y);
  acc.z = fmaf(dd2, hv.z, bv.z);
  acc.w = fmaf(dd2, hv.w, bv.w);

  int r0 = rowptr[d], r1 = rowptr[d+1];
  for (int base = r0; base < r1; base += 16) {
    int m = r1 - base;
    int sj = 0; float cj = 0.f;
    if (l16 < m) {
      int2 p = csr_sw[base + l16];
      sj = p.x;
      float w = (MODE == 2) ? 1.f : __int_as_float(p.y);
      cj = dinvW[sj] * w * dd;      // 0 if src or dst dead
    }
    #pragma unroll
    for (int j = 0; j < 16; ++j) {
      int s   = __shfl(sj, j, 16);
      float c = __shfl(cj, j, 16);
      if (c != 0.f) {
        float4 v = hB4[(size_t)s*16 + l16];
        acc.x = fmaf(c, v.x, acc.x);
        acc.y = fmaf(c, v.y, acc.y);
        acc.z = fmaf(c, v.z, acc.z);
        acc.w = fmaf(c, v.w, acc.w);
      }
    }
  }
  acc.x = fmaxf(acc.x, 0.f); acc.y = fmaxf(acc.y, 0.f);
  acc.z = fmaxf(acc.z, 0.f); acc.w = fmaxf(acc.w, 0.f);
  ((float4*)hA)[(size_t)d*16 + l16] = acc;

  float4 wp = ((const float4*)Wp)[l16];
  float dot = acc.x*wp.x + acc.y*wp.y + acc.z*wp.z + acc.w*wp.w;
  #pragma unroll
  for (int off = 8; off; off >>= 1) dot += __shfl_xor(dot, off, 16);
  if (l16 == 0) q[d] = dinvU[d] * dot;    // q = dinvU * (h . Wp); 0 at dead nodes
}

// ---------------- fused score + top-k + pool-scale + readout ----------------
__global__ __launch_bounds__(1024) void k_stk(
    const int* __restrict__ rowptr, const int2* __restrict__ csr_sw,
    const int* __restrict__ alive, const float* __restrict__ dinvU,
    const float* __restrict__ q, const float* __restrict__ bp,
    int k, float kf, float* __restrict__ h,
    int* __restrict__ aliveNext, float* __restrict__ g) {
  __shared__ float sq[NN];
  __shared__ float sc[NN];
  __shared__ float tm[NN];
  __shared__ float red1[16][FH];
  __shared__ float red2[16][FH];
  int b = blockIdx.x, t = threadIdx.x;
  int node = b*NN + t;
  sq[t] = q[node];
  __syncthreads();
  float du = dinvU[node];
  float sum = sq[t];                        // self: du*q[d] = du^2*sse
  int r0 = rowptr[node], r1 = rowptr[node+1];
  for (int j = r0; j < r1; ++j) sum += sq[csr_sw[j].x - b*NN];
  float raw = bp[0] + du*sum;               // dead: du=0 -> bp (masked below)
  int alv = alive[node];
  float me = alv ? raw : -INFINITY;
  sc[t] = me;
  __syncthreads();
  int rank = 0;
  const float4* sc4 = (const float4*)sc;
  for (int j4 = 0; j4 < NN/4; ++j4) {
    float4 o = sc4[j4];
    int jb = j4*4;
    rank += (o.x > me) || (o.x == me && jb+0 < t);
    rank += (o.y > me) || (o.y == me && jb+1 < t);
    rank += (o.z > me) || (o.z == me && jb+2 < t);
    rank += (o.w > me) || (o.w == me && jb+3 < t);
  }
  int sel = (rank < k) ? 1 : 0;
  aliveNext[node] = sel;
  __syncthreads();                          // everyone done reading sc
  tm[t] = sel ? tanhf(raw) : 0.f;
  sc[t] = sel ? 1.f : 0.f;
  __syncthreads();
  int f = t & 63, r = t >> 6;               // wave r handles nodes r, r+16, ...
  float mx = -INFINITY, sm = 0.f;
  float* hb = h + (size_t)b*NN*FH;
  for (int kk = 0; kk < 64; ++kk) {
    int n = r + kk*16;
    float tv = tm[n];
    size_t idx = (size_t)n*FH + f;
    float v = hb[idx] * tv;
    hb[idx] = v;
    if (sc[n] != 0.f) { mx = fmaxf(mx, v); sm += v; }
  }
  red1[r][f] = mx; red2[r][f] = sm;
  __syncthreads();
  if (t < FH) {
    float m2 = -INFINITY, s2 = 0.f;
    #pragma unroll
    for (int rr = 0; rr < 16; ++rr) { m2 = fmaxf(m2, red1[rr][t]); s2 += red2[rr][t]; }
    g[b*2*FH + t] += m2;
    g[b*2*FH + FH + t] += s2 / kf;
  }
}

// ---------------- MLP head + log_softmax ----------------
__global__ void k_mlp(const float* __restrict__ g,
                      const float* __restrict__ Wl1, const float* __restrict__ bl1,
                      const float* __restrict__ Wl2, const float* __restrict__ bl2,
                      const float* __restrict__ Wl3, const float* __restrict__ bl3,
                      float* __restrict__ out) {
  __shared__ float sg[2*FH];
  __shared__ float l1[FH];
  __shared__ float l2[FH/2];
  __shared__ float l3[2];
  int b = blockIdx.x, t = threadIdx.x;
  sg[t] = g[b*2*FH + t];
  sg[FH + t] = g[b*2*FH + FH + t];
  __syncthreads();
  float acc = bl1[t];
  #pragma unroll
  for (int k = 0; k < 2*FH; ++k) acc = fmaf(sg[k], Wl1[k*FH + t], acc);
  l1[t] = fmaxf(acc, 0.f);
  __syncthreads();
  if (t < 32) {
    float a2 = bl2[t];
    #pragma unroll
    for (int k = 0; k < FH; ++k) a2 = fmaf(l1[k], Wl2[k*32 + t], a2);
    l2[t] = fmaxf(a2, 0.f);
  }
  __syncthreads();
  if (t < 2) {
    float a3 = bl3[t];
    #pragma unroll
    for (int k = 0; k < 32; ++k) a3 = fmaf(l2[k], Wl3[k*2 + t], a3);
    l3[t] = a3;
  }
  __syncthreads();
  if (t == 0) {
    float m = fmaxf(l3[0], l3[1]);
    float lse = m + logf(expf(l3[0]-m) + expf(l3[1]-m));
    out[b*2+0] = l3[0] - lse;
    out[b*2+1] = l3[1] - lse;
  }
}

extern "C" void kernel_launch(void* const* d_in, const int* in_sizes, int n_in,
                              void* d_out, int out_size, void* d_ws, size_t ws_size,
                              hipStream_t stream) {
  const float* x   = (const float*)d_in[0];
  const float* ea  = (const float*)d_in[1];
  const float* W1  = (const float*)d_in[2];
  const float* b1  = (const float*)d_in[3];
  const float* Wp1 = (const float*)d_in[4];
  const float* bp1 = (const float*)d_in[5];
  const float* W2  = (const float*)d_in[6];
  const float* b2  = (const float*)d_in[7];
  const float* Wp2 = (const float*)d_in[8];
  const float* bp2 = (const float*)d_in[9];
  const float* W3  = (const float*)d_in[10];
  const float* b3  = (const float*)d_in[11];
  const float* Wp3 = (const float*)d_in[12];
  const float* bp3 = (const float*)d_in[13];
  const float* Wl1 = (const float*)d_in[14];
  const float* bl1 = (const float*)d_in[15];
  const float* Wl2 = (const float*)d_in[16];
  const float* bl2 = (const float*)d_in[17];
  const float* Wl3 = (const float*)d_in[18];
  const float* bl3 = (const float*)d_in[19];
  const int*   ei  = (const int*)d_in[20];
  float* out = (float*)d_out;

  // csr_sw FIRST: d_ws base is >=256B aligned -> int2 naturally aligned.
  int2* csr_sw = (int2*)d_ws;                        // NE
  float* hA    = (float*)(csr_sw + NE);              // BNODES*FH
  float* hB    = hA + (size_t)BNODES*FH;             // BNODES*FH
  float* dinvW = hB + (size_t)BNODES*FH;             // BNODES
  float* dinvU = dinvW + BNODES;                     // BNODES
  float* q     = dinvU + BNODES;                     // BNODES
  float* g     = q + BNODES;                         // NB*2*FH
  int* aliveA  = (int*)(g + NB*2*FH);                // BNODES
  int* aliveB  = aliveA + BNODES;                    // BNODES
  int* cnt     = aliveB + BNODES;                    // BNODES
  int* rowptr  = cnt + BNODES;                       // BNODES+1
  int* cursor  = rowptr + BNODES + 1;                // BNODES
  int* part    = cursor + BNODES;                    // 512
  int* poff    = part + 512;                         // 512

  const int TB = 256;
  const int gE  = NE / TB;
  const int gN  = BNODES / TB;         // 512
  const int gG  = BNODES / 16;         // 8192 blocks (16 nodes each)
  const int gNH = BNODES*FH / TB;      // 32768

  // CSR build
  k_init<<<gN, TB, 0, stream>>>(cnt, aliveA, g);
  k_count<<<gE, TB, 0, stream>>>(ei, cnt);
  k_scan1<<<512, 256, 0, stream>>>(cnt, part);
  k_scan2<<<1, 512, 0, stream>>>(part, poff);
  k_scan3<<<512, 256, 0, stream>>>(cnt, poff, rowptr, cursor);
  k_fill<<<gE, TB, 0, stream>>>(ei, ea, cursor, csr_sw);

  // ===== Layer 1 =====
  k_degs<0><<<gG, TB, 0, stream>>>(rowptr, csr_sw, aliveA, dinvW, dinvU);
  k_lin1<<<gNH, TB, 0, stream>>>(x, W1, hB);
  k_gather<0><<<gG, TB, 0, stream>>>(rowptr, csr_sw, dinvW, dinvU, hB, b1, Wp1, hA, q);
  k_stk<<<NB, NN, 0, stream>>>(rowptr, csr_sw, aliveA, dinvU, q, bp1, KK1, (float)KK1, hA, aliveB, g);

  // ===== Layer 2 =====
  k_degs<1><<<gG, TB, 0, stream>>>(rowptr, csr_sw, aliveB, dinvW, dinvU);
  k_lin64<<<4096, TB, 0, stream>>>(hA, W2, hB);
  k_gather<1><<<gG, TB, 0, stream>>>(rowptr, csr_sw, dinvW, dinvU, hB, b2, Wp2, hA, q);
  k_stk<<<NB, NN, 0, stream>>>(rowptr, csr_sw, aliveB, dinvU, q, bp2, KK2, (float)KK2, hA, aliveA, g);

  // ===== Layer 3 =====
  k_degs<2><<<gG, TB, 0, stream>>>(rowptr, csr_sw, aliveA, dinvW, dinvU);
  k_lin64<<<4096, TB, 0, stream>>>(hA, W3, hB);
  k_gather<2><<<gG, TB, 0, stream>>>(rowptr, csr_sw, dinvW, dinvU, hB, b3, Wp3, hA, q);
  k_stk<<<NB, NN, 0, stream>>>(rowptr, csr_sw, aliveA, dinvU, q, bp3, KK3, (float)KK3, hA, aliveB, g);

  k_mlp<<<NB, FH, 0, stream>>>(g, Wl1, bl1, Wl2, bl2, Wl3, bl3, out);
}

// Round 9
// 593.923 us; speedup vs baseline: 1.9934x; 1.0975x over previous
//
#include <hip/hip_runtime.h>
#include <math.h>

#define NB 128            // graphs
#define NN 1024           // nodes per graph
#define BNODES (NB*NN)    // 131072
#define NE 2097152        // edges
#define FH 64             // hidden
#define KK1 820
#define KK2 656
#define KK3 525

// ---------------- CSR build ----------------
__global__ void k_init(int* __restrict__ cnt, int* __restrict__ aliveA) {
  int i = blockIdx.x*256 + threadIdx.x;
  if (i < BNODES) { cnt[i] = 0; aliveA[i] = 1; }
}

__global__ void k_count(const int* __restrict__ ei, int* __restrict__ cnt) {
  int e = blockIdx.x*256 + threadIdx.x;
  if (e < NE) atomicAdd(&cnt[ei[NE + e]], 1);
}

__global__ void k_scan1(const int* __restrict__ cnt, int* __restrict__ part) {
  __shared__ int ps[256];
  int t = threadIdx.x;
  ps[t] = cnt[blockIdx.x*256 + t];
  __syncthreads();
  for (int off = 128; off > 0; off >>= 1) {
    if (t < off) ps[t] += ps[t + off];
    __syncthreads();
  }
  if (t == 0) part[blockIdx.x] = ps[0];
}

__global__ void k_scan2(const int* __restrict__ part, int* __restrict__ poff) {
  __shared__ int ps[512];
  int t = threadIdx.x;
  int v = part[t];
  ps[t] = v;
  __syncthreads();
  for (int off = 1; off < 512; off <<= 1) {
    int u = (t >= off) ? ps[t - off] : 0;
    __syncthreads();
    ps[t] += u;
    __syncthreads();
  }
  poff[t] = ps[t] - v;   // exclusive
}

__global__ void k_scan3(const int* __restrict__ cnt, const int* __restrict__ poff,
                        int* __restrict__ rowptr, int* __restrict__ cursor) {
  __shared__ int ps[256];
  int t = threadIdx.x, i = blockIdx.x*256 + t;
  int v = cnt[i];
  ps[t] = v;
  __syncthreads();
  for (int off = 1; off < 256; off <<= 1) {
    int u = (t >= off) ? ps[t - off] : 0;
    __syncthreads();
    ps[t] += u;
    __syncthreads();
  }
  int r = poff[blockIdx.x] + ps[t] - v;
  rowptr[i] = r;
  cursor[i] = r;
  if (i == BNODES - 1) rowptr[BNODES] = NE;
}

__global__ void k_fill(const int* __restrict__ ei, const float* __restrict__ ea,
                       int* __restrict__ cursor, int2* __restrict__ csr_sw) {
  int e = blockIdx.x*256 + threadIdx.x;
  if (e >= NE) return;
  int s = ei[e], d = ei[NE + e];
  int pos = atomicAdd(&cursor[d], 1);
  csr_sw[pos] = make_int2(s, __float_as_int(ea[e]));
}

// ---------------- degrees: 16-lane group per node ----------------
// MODE 0: w=ea, all alive | MODE 1: w=ea*mask | MODE 2: w=mask
// dead nodes get dinv=0 -> downstream coefficients self-mask.
template<int MODE>
__global__ void k_degs(const int* __restrict__ rowptr, const int2* __restrict__ csr_sw,
                       const int* __restrict__ alive,
                       float* __restrict__ dinvW, float* __restrict__ dinvU) {
  int t = threadIdx.x;
  int l16 = t & 15;
  int d = blockIdx.x*16 + (t >> 4);
  int r0 = rowptr[d], r1 = rowptr[d+1];
  float sW = 0.f, sU = 0.f;
  for (int base = r0; base < r1; base += 16) {
    if (base + l16 < r1) {
      int2 p = csr_sw[base + l16];
      bool ok = (MODE == 0) || (alive[p.x] != 0);
      if (ok) { sW += (MODE == 2) ? 1.f : __int_as_float(p.y); sU += 1.f; }
    }
  }
  #pragma unroll
  for (int off = 8; off; off >>= 1) {
    sW += __shfl_xor(sW, off, 16);
    sU += __shfl_xor(sU, off, 16);
  }
  if (l16 == 0) {
    bool dA = (MODE == 0) || (alive[d] != 0);
    dinvW[d] = dA ? rsqrtf(1.f + sW) : 0.f;
    dinvU[d] = dA ? rsqrtf(1.f + sU) : 0.f;
  }
}

// ---------------- layer-1 input transform (2 -> 64) ----------------
__global__ void k_lin1(const float* __restrict__ x, const float* __restrict__ W,
                       float* __restrict__ h) {
  int i = blockIdx.x*256 + threadIdx.x;
  if (i >= BNODES*FH) return;
  int node = i >> 6, f = i & 63;
  h[i] = x[2*node]*W[f] + x[2*node+1]*W[FH + f];
}

// ---------------- fused pool-scale + 64x64 linear ----------------
// hB[n] = (tm[n] * hA[n]) @ W. 64-node tile in LDS, 4 threads/node x 16 outputs.
__global__ void k_lin64(const float* __restrict__ hA, const float* __restrict__ tm,
                        const float* __restrict__ W, float* __restrict__ hB) {
  __shared__ float sX[64][65];     // +1 pad: node-major reads conflict-free
  __shared__ float sW[64*64];
  int t = threadIdx.x;
  for (int i = t; i < 1024; i += 256) ((float4*)sW)[i] = ((const float4*)W)[i];
  int nb = blockIdx.x * 64;        // node base
  #pragma unroll
  for (int i = 0; i < 16; ++i) {
    int gidx = (nb << 6) + i*256 + t;       // coalesced
    int node = gidx >> 6, f = gidx & 63;
    sX[node - nb][f] = hA[gidx] * tm[node];
  }
  __syncthreads();
  int node = t >> 2;               // 0..63
  int f0 = (t & 3) * 16;
  float4 a0 = {0,0,0,0}, a1 = a0, a2 = a0, a3 = a0;
  #pragma unroll 4
  for (int k = 0; k < 64; ++k) {
    float xv = sX[node][k];
    const float4 w0 = *(const float4*)&sW[k*64 + f0];
    const float4 w1 = *(const float4*)&sW[k*64 + f0 + 4];
    const float4 w2 = *(const float4*)&sW[k*64 + f0 + 8];
    const float4 w3 = *(const float4*)&sW[k*64 + f0 + 12];
    a0.x = fmaf(xv, w0.x, a0.x); a0.y = fmaf(xv, w0.y, a0.y);
    a0.z = fmaf(xv, w0.z, a0.z); a0.w = fmaf(xv, w0.w, a0.w);
    a1.x = fmaf(xv, w1.x, a1.x); a1.y = fmaf(xv, w1.y, a1.y);
    a1.z = fmaf(xv, w1.z, a1.z); a1.w = fmaf(xv, w1.w, a1.w);
    a2.x = fmaf(xv, w2.x, a2.x); a2.y = fmaf(xv, w2.y, a2.y);
    a2.z = fmaf(xv, w2.z, a2.z); a2.w = fmaf(xv, w2.w, a2.w);
    a3.x = fmaf(xv, w3.x, a3.x); a3.y = fmaf(xv, w3.y, a3.y);
    a3.z = fmaf(xv, w3.z, a3.z); a3.w = fmaf(xv, w3.w, a3.w);
  }
  float4* dst = (float4*)(hB + (size_t)(nb + node)*FH + f0);
  dst[0] = a0; dst[1] = a1; dst[2] = a2; dst[3] = a3;
}

// ---------------- fused GCN gather (4 nodes/wave, float4/lane) ----------------
template<int MODE>
__global__ void k_gather(const int* __restrict__ rowptr, const int2* __restrict__ csr_sw,
                         const float* __restrict__ dinvW, const float* __restrict__ dinvU,
                         const float* __restrict__ hB, const float* __restrict__ b,
                         const float* __restrict__ Wp,
                         float* __restrict__ hA, float* __restrict__ q) {
  int cpx = gridDim.x >> 3;
  int blk = (blockIdx.x & 7) * cpx + (blockIdx.x >> 3);   // XCD swizzle (grid%8==0)
  int t = threadIdx.x;
  int l16 = t & 15;
  int d = blk*16 + (t >> 4);
  const float4* hB4 = (const float4*)hB;

  float dd = dinvW[d];
  float4 hv = hB4[(size_t)d*16 + l16];
  float4 bv = ((const float4*)b)[l16];
  float dd2 = dd*dd;
  float4 acc;
  acc.x = fmaf(dd2, hv.x, bv.x);
  acc.y = fmaf(dd2, hv.y, bv.y);
  acc.z = fmaf(dd2, hv.z, bv.z);
  acc.w = fmaf(dd2, hv.w, bv.w);

  int r0 = rowptr[d], r1 = rowptr[d+1];
  for (int base = r0; base < r1; base += 16) {
    int m = r1 - base;
    int sj = 0; float cj = 0.f;
    if (l16 < m) {
      int2 p = csr_sw[base + l16];
      sj = p.x;
      float w = (MODE == 2) ? 1.f : __int_as_float(p.y);
      cj = dinvW[sj] * w * dd;      // 0 if src or dst dead
    }
    #pragma unroll
    for (int j = 0; j < 16; ++j) {
      int s   = __shfl(sj, j, 16);
      float c = __shfl(cj, j, 16);
      if (c != 0.f) {
        float4 v = hB4[(size_t)s*16 + l16];
        acc.x = fmaf(c, v.x, acc.x);
        acc.y = fmaf(c, v.y, acc.y);
        acc.z = fmaf(c, v.z, acc.z);
        acc.w = fmaf(c, v.w, acc.w);
      }
    }
  }
  acc.x = fmaxf(acc.x, 0.f); acc.y = fmaxf(acc.y, 0.f);
  acc.z = fmaxf(acc.z, 0.f); acc.w = fmaxf(acc.w, 0.f);
  ((float4*)hA)[(size_t)d*16 + l16] = acc;

  float4 wp = ((const float4*)Wp)[l16];
  float dot = acc.x*wp.x + acc.y*wp.y + acc.z*wp.z + acc.w*wp.w;
  #pragma unroll
  for (int off = 8; off; off >>= 1) dot += __shfl_xor(dot, off, 16);
  if (l16 == 0) q[d] = dinvU[d] * dot;    // q = dinvU*(h.Wp); 0 at dead nodes
}

// ---------------- scoring aggregation (q is self-masking) ----------------
__global__ void k_score(const int* __restrict__ rowptr, const int2* __restrict__ csr_sw,
                        const float* __restrict__ dinvU, const float* __restrict__ q,
                        const float* __restrict__ bp, float* __restrict__ score) {
  int t = threadIdx.x;
  int l16 = t & 15;
  int d = blockIdx.x*16 + (t >> 4);
  float du = dinvU[d];
  float sum = 0.f;
  if (du != 0.f) {
    int r0 = rowptr[d], r1 = rowptr[d+1];
    for (int base = r0; base < r1; base += 16)
      if (base + l16 < r1) sum += q[csr_sw[base + l16].x];
  }
  #pragma unroll
  for (int off = 8; off; off >>= 1) sum += __shfl_xor(sum, off, 16);
  if (l16 == 0) score[d] = bp[0] + du*(q[d] + sum);
}

// ---------------- per-graph top-k rank (exact jax.lax.top_k ties) ----------------
__global__ __launch_bounds__(1024) void k_topk(const float* __restrict__ score,
                                               const int* __restrict__ alive, int k,
                                               float* __restrict__ tm,
                                               int* __restrict__ aliveNext) {
  __shared__ float sc[NN];
  int b = blockIdx.x, t = threadIdx.x;
  int node = b*NN + t;
  float raw = score[node];
  float me = alive[node] ? raw : -INFINITY;
  sc[t] = me;
  __syncthreads();
  int rank = 0;
  const float4* sc4 = (const float4*)sc;
  for (int j4 = 0; j4 < NN/4; ++j4) {
    float4 o = sc4[j4];
    int jb = j4*4;
    rank += (o.x > me) || (o.x == me && jb+0 < t);
    rank += (o.y > me) || (o.y == me && jb+1 < t);
    rank += (o.z > me) || (o.z == me && jb+2 < t);
    rank += (o.w > me) || (o.w == me && jb+3 < t);
  }
  int sel = (rank < k) ? 1 : 0;
  aliveNext[node] = sel;
  tm[node] = sel ? tanhf(raw) : 0.f;
}

// ---------------- pool-scale (virtual) + partial readout ----------------
// 4 blocks per graph; partials pmax/psum: [NB][4][FH]. Scaled h never written.
__global__ void k_sread(const float* __restrict__ hA, const float* __restrict__ tm,
                        const int* __restrict__ aliveN,
                        float* __restrict__ pmax, float* __restrict__ psum) {
  __shared__ float rm[4][FH], rs[4][FH];
  int b = blockIdx.x >> 2, p = blockIdx.x & 3;
  int t = threadIdx.x, f = t & 63, r = t >> 6;
  float mx = -INFINITY, sm = 0.f;
  for (int i = 0; i < 64; ++i) {
    int n = p*256 + i*4 + r;
    int node = b*NN + n;
    float v = hA[(size_t)node*FH + f] * tm[node];
    if (aliveN[node]) { mx = fmaxf(mx, v); sm += v; }
  }
  rm[r][f] = mx; rs[r][f] = sm;
  __syncthreads();
  if (t < FH) {
    float m2 = fmaxf(fmaxf(rm[0][t], rm[1][t]), fmaxf(rm[2][t], rm[3][t]));
    float s2 = rs[0][t] + rs[1][t] + rs[2][t] + rs[3][t];
    pmax[(b*4 + p)*FH + t] = m2;
    psum[(b*4 + p)*FH + t] = s2;
  }
}

// ---------------- partial reduce + MLP head + log_softmax ----------------
__global__ void k_mlp(const float* __restrict__ pmax, const float* __restrict__ psum,
                      const float* __restrict__ Wl1, const float* __restrict__ bl1,
                      const float* __restrict__ Wl2, const float* __restrict__ bl2,
                      const float* __restrict__ Wl3, const float* __restrict__ bl3,
                      float* __restrict__ out) {
  __shared__ float sg[2*FH];
  __shared__ float l1[FH];
  __shared__ float l2[FH/2];
  __shared__ float l3[2];
  int b = blockIdx.x, t = threadIdx.x;
  const float kf[3] = {(float)KK1, (float)KK2, (float)KK3};
  float gm = 0.f, gs = 0.f;
  #pragma unroll
  for (int l = 0; l < 3; ++l) {
    const float* pm = pmax + (size_t)l*NB*4*FH + (b*4)*FH;
    const float* ps = psum + (size_t)l*NB*4*FH + (b*4)*FH;
    float mm = -INFINITY, ss = 0.f;
    #pragma unroll
    for (int p = 0; p < 4; ++p) {
      mm = fmaxf(mm, pm[p*FH + t]);
      ss += ps[p*FH + t];
    }
    gm += mm;
    gs += ss / kf[l];
  }
  sg[t] = gm;
  sg[FH + t] = gs;
  __syncthreads();
  float acc = bl1[t];
  #pragma unroll
  for (int k = 0; k < 2*FH; ++k) acc = fmaf(sg[k], Wl1[k*FH + t], acc);
  l1[t] = fmaxf(acc, 0.f);
  __syncthreads();
  if (t < 32) {
    float a2 = bl2[t];
    #pragma unroll
    for (int k = 0; k < FH; ++k) a2 = fmaf(l1[k], Wl2[k*32 + t], a2);
    l2[t] = fmaxf(a2, 0.f);
  }
  __syncthreads();
  if (t < 2) {
    float a3 = bl3[t];
    #pragma unroll
    for (int k = 0; k < 32; ++k) a3 = fmaf(l2[k], Wl3[k*2 + t], a3);
    l3[t] = a3;
  }
  __syncthreads();
  if (t == 0) {
    float m = fmaxf(l3[0], l3[1]);
    float lse = m + logf(expf(l3[0]-m) + expf(l3[1]-m));
    out[b*2+0] = l3[0] - lse;
    out[b*2+1] = l3[1] - lse;
  }
}

extern "C" void kernel_launch(void* const* d_in, const int* in_sizes, int n_in,
                              void* d_out, int out_size, void* d_ws, size_t ws_size,
                              hipStream_t stream) {
  const float* x   = (const float*)d_in[0];
  const float* ea  = (const float*)d_in[1];
  const float* W1  = (const float*)d_in[2];
  const float* b1  = (const float*)d_in[3];
  const float* Wp1 = (const float*)d_in[4];
  const float* bp1 = (const float*)d_in[5];
  const float* W2  = (const float*)d_in[6];
  const float* b2  = (const float*)d_in[7];
  const float* Wp2 = (const float*)d_in[8];
  const float* bp2 = (const float*)d_in[9];
  const float* W3  = (const float*)d_in[10];
  const float* b3  = (const float*)d_in[11];
  const float* Wp3 = (const float*)d_in[12];
  const float* bp3 = (const float*)d_in[13];
  const float* Wl1 = (const float*)d_in[14];
  const float* bl1 = (const float*)d_in[15];
  const float* Wl2 = (const float*)d_in[16];
  const float* bl2 = (const float*)d_in[17];
  const float* Wl3 = (const float*)d_in[18];
  const float* bl3 = (const float*)d_in[19];
  const int*   ei  = (const int*)d_in[20];
  float* out = (float*)d_out;

  // csr_sw first: d_ws base aligned -> int2 naturally aligned.
  int2* csr_sw = (int2*)d_ws;                        // NE
  float* hA    = (float*)(csr_sw + NE);              // BNODES*FH
  float* hB    = hA + (size_t)BNODES*FH;             // BNODES*FH
  float* dinvW = hB + (size_t)BNODES*FH;             // BNODES
  float* dinvU = dinvW + BNODES;                     // BNODES
  float* q     = dinvU + BNODES;                     // BNODES
  float* score = q + BNODES;                         // BNODES
  float* tm    = score + BNODES;                     // BNODES
  float* pmax  = tm + BNODES;                        // 3*NB*4*FH
  float* psum  = pmax + 3*NB*4*FH;                   // 3*NB*4*FH
  int* aliveA  = (int*)(psum + 3*NB*4*FH);           // BNODES
  int* aliveB  = aliveA + BNODES;                    // BNODES
  int* cnt     = aliveB + BNODES;                    // BNODES
  int* rowptr  = cnt + BNODES;                       // BNODES+1
  int* cursor  = rowptr + BNODES + 1;                // BNODES
  int* part    = cursor + BNODES;                    // 512
  int* poff    = part + 512;                         // 512

  const int TB = 256;
  const int gE  = NE / TB;
  const int gN  = BNODES / TB;         // 512
  const int gG  = BNODES / 16;         // 8192 (16 nodes/block)
  const int gNH = BNODES*FH / TB;      // 32768
  const int gL  = BNODES / 64;         // 2048 lin64 blocks

  // CSR build
  k_init<<<gN, TB, 0, stream>>>(cnt, aliveA);
  k_count<<<gE, TB, 0, stream>>>(ei, cnt);
  k_scan1<<<512, 256, 0, stream>>>(cnt, part);
  k_scan2<<<1, 512, 0, stream>>>(part, poff);
  k_scan3<<<512, 256, 0, stream>>>(cnt, poff, rowptr, cursor);
  k_fill<<<gE, TB, 0, stream>>>(ei, ea, cursor, csr_sw);

  // ===== Layer 1 =====
  k_degs<0><<<gG, TB, 0, stream>>>(rowptr, csr_sw, aliveA, dinvW, dinvU);
  k_lin1<<<gNH, TB, 0, stream>>>(x, W1, hB);
  k_gather<0><<<gG, TB, 0, stream>>>(rowptr, csr_sw, dinvW, dinvU, hB, b1, Wp1, hA, q);
  k_score<<<gG, TB, 0, stream>>>(rowptr, csr_sw, dinvU, q, bp1, score);
  k_topk<<<NB, 1024, 0, stream>>>(score, aliveA, KK1, tm, aliveB);
  k_sread<<<NB*4, TB, 0, stream>>>(hA, tm, aliveB, pmax, psum);

  // ===== Layer 2 =====
  k_degs<1><<<gG, TB, 0, stream>>>(rowptr, csr_sw, aliveB, dinvW, dinvU);
  k_lin64<<<gL, TB, 0, stream>>>(hA, tm, W2, hB);
  k_gather<1><<<gG, TB, 0, stream>>>(rowptr, csr_sw, dinvW, dinvU, hB, b2, Wp2, hA, q);
  k_score<<<gG, TB, 0, stream>>>(rowptr, csr_sw, dinvU, q, bp2, score);
  k_topk<<<NB, 1024, 0, stream>>>(score, aliveB, KK2, tm, aliveA);
  k_sread<<<NB*4, TB, 0, stream>>>(hA, tm, aliveA, pmax + NB*4*FH, psum + NB*4*FH);

  // ===== Layer 3 =====
  k_degs<2><<<gG, TB, 0, stream>>>(rowptr, csr_sw, aliveA, dinvW, dinvU);
  k_lin64<<<gL, TB, 0, stream>>>(hA, tm, W3, hB);
  k_gather<2><<<gG, TB, 0, stream>>>(rowptr, csr_sw, dinvW, dinvU, hB, b3, Wp3, hA, q);
  k_score<<<gG, TB, 0, stream>>>(rowptr, csr_sw, dinvU, q, bp3, score);
  k_topk<<<NB, 1024, 0, stream>>>(score, aliveA, KK3, tm, aliveB);
  k_sread<<<NB*4, TB, 0, stream>>>(hA, tm, aliveB, pmax + 2*NB*4*FH, psum + 2*NB*4*FH);

  k_mlp<<<NB, FH, 0, stream>>>(pmax, psum, Wl1, bl1, Wl2, bl2, Wl3, bl3, out);
}

// Round 10
// 490.603 us; speedup vs baseline: 2.4133x; 1.2106x over previous
//
#include <hip/hip_runtime.h>
#include <math.h>

#define NB 128            // graphs
#define NN 1024           // nodes per graph
#define BNODES (NB*NN)    // 131072
#define NE 2097152        // edges
#define EPG (NE/NB)       // 16384 edges per graph (edge list is graph-blocked)
#define FH 64             // hidden
#define KK1 820
#define KK2 656
#define KK3 525

// ---------------- one-kernel CSR build: one block per graph ----------------
// Edge e of graph b lies in [b*EPG,(b+1)*EPG); dst in [b*NN,(b+1)*NN).
// LDS count -> LDS scan -> LDS-cursor fill. No global atomics.
__global__ __launch_bounds__(1024) void k_csr(const int* __restrict__ ei,
                                              const float* __restrict__ ea,
                                              int* __restrict__ rowptr,
                                              int2* __restrict__ csr_sw,
                                              int* __restrict__ aliveA) {
  __shared__ int cnt[NN];
  __shared__ int cur[NN];
  int b = blockIdx.x, t = threadIdx.x;
  aliveA[b*NN + t] = 1;
  cnt[t] = 0;
  __syncthreads();
  int ebase = b*EPG;
  #pragma unroll
  for (int i = 0; i < EPG/NN; ++i) {
    int e = ebase + i*NN + t;
    atomicAdd(&cnt[ei[NE + e] - b*NN], 1);
  }
  __syncthreads();
  // in-place Hillis-Steele inclusive scan (read/write separated by barriers)
  int v = cnt[t];
  for (int off = 1; off < NN; off <<= 1) {
    int u = (t >= off) ? cnt[t - off] : 0;
    __syncthreads();
    cnt[t] += u;
    __syncthreads();
  }
  int excl = cnt[t] - v;
  rowptr[b*NN + t] = ebase + excl;
  cur[t] = excl;
  if (b == NB-1 && t == NN-1) rowptr[BNODES] = NE;
  __syncthreads();
  #pragma unroll
  for (int i = 0; i < EPG/NN; ++i) {
    int e = ebase + i*NN + t;
    int s = ei[e];
    int d = ei[NE + e] - b*NN;
    float w = ea[e];
    int pos = atomicAdd(&cur[d], 1);
    csr_sw[ebase + pos] = make_int2(s, __float_as_int(w));
  }
}

// ---------------- degrees: 16-lane group per node ----------------
// MODE 0: w=ea, all alive | MODE 1: w=ea*mask | MODE 2: w=mask
// dead nodes get dinv=0 -> downstream coefficients self-mask.
template<int MODE>
__global__ void k_degs(const int* __restrict__ rowptr, const int2* __restrict__ csr_sw,
                       const int* __restrict__ alive,
                       float* __restrict__ dinvW, float* __restrict__ dinvU) {
  int t = threadIdx.x;
  int l16 = t & 15;
  int d = blockIdx.x*16 + (t >> 4);
  int r0 = rowptr[d], r1 = rowptr[d+1];
  float sW = 0.f, sU = 0.f;
  for (int base = r0; base < r1; base += 16) {
    if (base + l16 < r1) {
      int2 p = csr_sw[base + l16];
      bool ok = (MODE == 0) || (alive[p.x] != 0);
      if (ok) { sW += (MODE == 2) ? 1.f : __int_as_float(p.y); sU += 1.f; }
    }
  }
  #pragma unroll
  for (int off = 8; off; off >>= 1) {
    sW += __shfl_xor(sW, off, 16);
    sU += __shfl_xor(sU, off, 16);
  }
  if (l16 == 0) {
    bool dA = (MODE == 0) || (alive[d] != 0);
    dinvW[d] = dA ? rsqrtf(1.f + sW) : 0.f;
    dinvU[d] = dA ? rsqrtf(1.f + sU) : 0.f;
  }
}

// ---------------- layer-1 input transform (2 -> 64) ----------------
__global__ void k_lin1(const float* __restrict__ x, const float* __restrict__ W,
                       float* __restrict__ h) {
  int i = blockIdx.x*256 + threadIdx.x;
  if (i >= BNODES*FH) return;
  int node = i >> 6, f = i & 63;
  h[i] = x[2*node]*W[f] + x[2*node+1]*W[FH + f];
}

// ---------------- fused pool-scale + 64x64 linear ----------------
__global__ void k_lin64(const float* __restrict__ hA, const float* __restrict__ tm,
                        const float* __restrict__ W, float* __restrict__ hB) {
  __shared__ float sX[64][65];
  __shared__ float sW[64*64];
  int t = threadIdx.x;
  for (int i = t; i < 1024; i += 256) ((float4*)sW)[i] = ((const float4*)W)[i];
  int nb = blockIdx.x * 64;
  #pragma unroll
  for (int i = 0; i < 16; ++i) {
    int gidx = (nb << 6) + i*256 + t;
    int node = gidx >> 6, f = gidx & 63;
    sX[node - nb][f] = hA[gidx] * tm[node];
  }
  __syncthreads();
  int node = t >> 2;
  int f0 = (t & 3) * 16;
  float4 a0 = {0,0,0,0}, a1 = a0, a2 = a0, a3 = a0;
  #pragma unroll 4
  for (int k = 0; k < 64; ++k) {
    float xv = sX[node][k];
    const float4 w0 = *(const float4*)&sW[k*64 + f0];
    const float4 w1 = *(const float4*)&sW[k*64 + f0 + 4];
    const float4 w2 = *(const float4*)&sW[k*64 + f0 + 8];
    const float4 w3 = *(const float4*)&sW[k*64 + f0 + 12];
    a0.x = fmaf(xv, w0.x, a0.x); a0.y = fmaf(xv, w0.y, a0.y);
    a0.z = fmaf(xv, w0.z, a0.z); a0.w = fmaf(xv, w0.w, a0.w);
    a1.x = fmaf(xv, w1.x, a1.x); a1.y = fmaf(xv, w1.y, a1.y);
    a1.z = fmaf(xv, w1.z, a1.z); a1.w = fmaf(xv, w1.w, a1.w);
    a2.x = fmaf(xv, w2.x, a2.x); a2.y = fmaf(xv, w2.y, a2.y);
    a2.z = fmaf(xv, w2.z, a2.z); a2.w = fmaf(xv, w2.w, a2.w);
    a3.x = fmaf(xv, w3.x, a3.x); a3.y = fmaf(xv, w3.y, a3.y);
    a3.z = fmaf(xv, w3.z, a3.z); a3.w = fmaf(xv, w3.w, a3.w);
  }
  float4* dst = (float4*)(hB + (size_t)(nb + node)*FH + f0);
  dst[0] = a0; dst[1] = a1; dst[2] = a2; dst[3] = a3;
}

// ---------------- fused GCN gather (4 nodes/wave, float4/lane) ----------------
template<int MODE>
__global__ void k_gather(const int* __restrict__ rowptr, const int2* __restrict__ csr_sw,
                         const float* __restrict__ dinvW, const float* __restrict__ dinvU,
                         const float* __restrict__ hB, const float* __restrict__ b,
                         const float* __restrict__ Wp,
                         float* __restrict__ hA, float* __restrict__ q) {
  int cpx = gridDim.x >> 3;
  int blk = (blockIdx.x & 7) * cpx + (blockIdx.x >> 3);   // XCD swizzle (grid%8==0)
  int t = threadIdx.x;
  int l16 = t & 15;
  int d = blk*16 + (t >> 4);
  const float4* hB4 = (const float4*)hB;

  float dd = dinvW[d];
  float4 hv = hB4[(size_t)d*16 + l16];
  float4 bv = ((const float4*)b)[l16];
  float dd2 = dd*dd;
  float4 acc;
  acc.x = fmaf(dd2, hv.x, bv.x);
  acc.y = fmaf(dd2, hv.y, bv.y);
  acc.z = fmaf(dd2, hv.z, bv.z);
  acc.w = fmaf(dd2, hv.w, bv.w);

  int r0 = rowptr[d], r1 = rowptr[d+1];
  for (int base = r0; base < r1; base += 16) {
    int m = r1 - base;
    int sj = 0; float cj = 0.f;
    if (l16 < m) {
      int2 p = csr_sw[base + l16];
      sj = p.x;
      float w = (MODE == 2) ? 1.f : __int_as_float(p.y);
      cj = dinvW[sj] * w * dd;      // 0 if src or dst dead
    }
    #pragma unroll
    for (int j = 0; j < 16; ++j) {
      int s   = __shfl(sj, j, 16);
      float c = __shfl(cj, j, 16);
      if (c != 0.f) {
        float4 v = hB4[(size_t)s*16 + l16];
        acc.x = fmaf(c, v.x, acc.x);
        acc.y = fmaf(c, v.y, acc.y);
        acc.z = fmaf(c, v.z, acc.z);
        acc.w = fmaf(c, v.w, acc.w);
      }
    }
  }
  acc.x = fmaxf(acc.x, 0.f); acc.y = fmaxf(acc.y, 0.f);
  acc.z = fmaxf(acc.z, 0.f); acc.w = fmaxf(acc.w, 0.f);
  ((float4*)hA)[(size_t)d*16 + l16] = acc;

  float4 wp = ((const float4*)Wp)[l16];
  float dot = acc.x*wp.x + acc.y*wp.y + acc.z*wp.z + acc.w*wp.w;
  #pragma unroll
  for (int off = 8; off; off >>= 1) dot += __shfl_xor(dot, off, 16);
  if (l16 == 0) q[d] = dinvU[d] * dot;    // q = dinvU*(h.Wp); 0 at dead nodes
}

// ---------------- scoring aggregation (q is self-masking) ----------------
__global__ void k_score(const int* __restrict__ rowptr, const int2* __restrict__ csr_sw,
                        const float* __restrict__ dinvU, const float* __restrict__ q,
                        const float* __restrict__ bp, float* __restrict__ score) {
  int t = threadIdx.x;
  int l16 = t & 15;
  int d = blockIdx.x*16 + (t >> 4);
  float du = dinvU[d];
  float sum = 0.f;
  if (du != 0.f) {
    int r0 = rowptr[d], r1 = rowptr[d+1];
    for (int base = r0; base < r1; base += 16)
      if (base + l16 < r1) sum += q[csr_sw[base + l16].x];
  }
  #pragma unroll
  for (int off = 8; off; off >>= 1) sum += __shfl_xor(sum, off, 16);
  if (l16 == 0) score[d] = bp[0] + du*(q[d] + sum);
}

// ---------------- per-graph top-k rank (exact jax.lax.top_k ties) ----------------
__global__ __launch_bounds__(1024) void k_topk(const float* __restrict__ score,
                                               const int* __restrict__ alive, int k,
                                               float* __restrict__ tm,
                                               int* __restrict__ aliveNext) {
  __shared__ float sc[NN];
  int b = blockIdx.x, t = threadIdx.x;
  int node = b*NN + t;
  float raw = score[node];
  float me = alive[node] ? raw : -INFINITY;
  sc[t] = me;
  __syncthreads();
  int rank = 0;
  const float4* sc4 = (const float4*)sc;
  for (int j4 = 0; j4 < NN/4; ++j4) {
    float4 o = sc4[j4];
    int jb = j4*4;
    rank += (o.x > me) || (o.x == me && jb+0 < t);
    rank += (o.y > me) || (o.y == me && jb+1 < t);
    rank += (o.z > me) || (o.z == me && jb+2 < t);
    rank += (o.w > me) || (o.w == me && jb+3 < t);
  }
  int sel = (rank < k) ? 1 : 0;
  aliveNext[node] = sel;
  tm[node] = sel ? tanhf(raw) : 0.f;
}

// ---------------- pool-scale (virtual) + partial readout ----------------
__global__ void k_sread(const float* __restrict__ hA, const float* __restrict__ tm,
                        const int* __restrict__ aliveN,
                        float* __restrict__ pmax, float* __restrict__ psum) {
  __shared__ float rm[4][FH], rs[4][FH];
  int b = blockIdx.x >> 2, p = blockIdx.x & 3;
  int t = threadIdx.x, f = t & 63, r = t >> 6;
  float mx = -INFINITY, sm = 0.f;
  for (int i = 0; i < 64; ++i) {
    int n = p*256 + i*4 + r;
    int node = b*NN + n;
    float v = hA[(size_t)node*FH + f] * tm[node];
    if (aliveN[node]) { mx = fmaxf(mx, v); sm += v; }
  }
  rm[r][f] = mx; rs[r][f] = sm;
  __syncthreads();
  if (t < FH) {
    float m2 = fmaxf(fmaxf(rm[0][t], rm[1][t]), fmaxf(rm[2][t], rm[3][t]));
    float s2 = rs[0][t] + rs[1][t] + rs[2][t] + rs[3][t];
    pmax[(b*4 + p)*FH + t] = m2;
    psum[(b*4 + p)*FH + t] = s2;
  }
}

// ---------------- partial reduce + MLP head + log_softmax ----------------
__global__ void k_mlp(const float* __restrict__ pmax, const float* __restrict__ psum,
                      const float* __restrict__ Wl1, const float* __restrict__ bl1,
                      const float* __restrict__ Wl2, const float* __restrict__ bl2,
                      const float* __restrict__ Wl3, const float* __restrict__ bl3,
                      float* __restrict__ out) {
  __shared__ float sg[2*FH];
  __shared__ float l1[FH];
  __shared__ float l2[FH/2];
  __shared__ float l3[2];
  int b = blockIdx.x, t = threadIdx.x;
  const float kf[3] = {(float)KK1, (float)KK2, (float)KK3};
  float gm = 0.f, gs = 0.f;
  #pragma unroll
  for (int l = 0; l < 3; ++l) {
    const float* pm = pmax + (size_t)l*NB*4*FH + (b*4)*FH;
    const float* ps = psum + (size_t)l*NB*4*FH + (b*4)*FH;
    float mm = -INFINITY, ss = 0.f;
    #pragma unroll
    for (int p = 0; p < 4; ++p) {
      mm = fmaxf(mm, pm[p*FH + t]);
      ss += ps[p*FH + t];
    }
    gm += mm;
    gs += ss / kf[l];
  }
  sg[t] = gm;
  sg[FH + t] = gs;
  __syncthreads();
  float acc = bl1[t];
  #pragma unroll
  for (int k = 0; k < 2*FH; ++k) acc = fmaf(sg[k], Wl1[k*FH + t], acc);
  l1[t] = fmaxf(acc, 0.f);
  __syncthreads();
  if (t < 32) {
    float a2 = bl2[t];
    #pragma unroll
    for (int k = 0; k < FH; ++k) a2 = fmaf(l1[k], Wl2[k*32 + t], a2);
    l2[t] = fmaxf(a2, 0.f);
  }
  __syncthreads();
  if (t < 2) {
    float a3 = bl3[t];
    #pragma unroll
    for (int k = 0; k < 32; ++k) a3 = fmaf(l2[k], Wl3[k*2 + t], a3);
    l3[t] = a3;
  }
  __syncthreads();
  if (t == 0) {
    float m = fmaxf(l3[0], l3[1]);
    float lse = m + logf(expf(l3[0]-m) + expf(l3[1]-m));
    out[b*2+0] = l3[0] - lse;
    out[b*2+1] = l3[1] - lse;
  }
}

extern "C" void kernel_launch(void* const* d_in, const int* in_sizes, int n_in,
                              void* d_out, int out_size, void* d_ws, size_t ws_size,
                              hipStream_t stream) {
  const float* x   = (const float*)d_in[0];
  const float* ea  = (const float*)d_in[1];
  const float* W1  = (const float*)d_in[2];
  const float* b1  = (const float*)d_in[3];
  const float* Wp1 = (const float*)d_in[4];
  const float* bp1 = (const float*)d_in[5];
  const float* W2  = (const float*)d_in[6];
  const float* b2  = (const float*)d_in[7];
  const float* Wp2 = (const float*)d_in[8];
  const float* bp2 = (const float*)d_in[9];
  const float* W3  = (const float*)d_in[10];
  const float* b3  = (const float*)d_in[11];
  const float* Wp3 = (const float*)d_in[12];
  const float* bp3 = (const float*)d_in[13];
  const float* Wl1 = (const float*)d_in[14];
  const float* bl1 = (const float*)d_in[15];
  const float* Wl2 = (const float*)d_in[16];
  const float* bl2 = (const float*)d_in[17];
  const float* Wl3 = (const float*)d_in[18];
  const float* bl3 = (const float*)d_in[19];
  const int*   ei  = (const int*)d_in[20];
  float* out = (float*)d_out;

  // csr_sw first: d_ws base aligned -> int2 naturally aligned.
  int2* csr_sw = (int2*)d_ws;                        // NE
  float* hA    = (float*)(csr_sw + NE);              // BNODES*FH
  float* hB    = hA + (size_t)BNODES*FH;             // BNODES*FH
  float* dinvW = hB + (size_t)BNODES*FH;             // BNODES
  float* dinvU = dinvW + BNODES;                     // BNODES
  float* q     = dinvU + BNODES;                     // BNODES
  float* score = q + BNODES;                         // BNODES
  float* tm    = score + BNODES;                     // BNODES
  float* pmax  = tm + BNODES;                        // 3*NB*4*FH
  float* psum  = pmax + 3*NB*4*FH;                   // 3*NB*4*FH
  int* aliveA  = (int*)(psum + 3*NB*4*FH);           // BNODES
  int* aliveB  = aliveA + BNODES;                    // BNODES
  int* rowptr  = aliveB + BNODES;                    // BNODES+1

  const int TB = 256;
  const int gG  = BNODES / 16;         // 8192 (16 nodes/block)
  const int gNH = BNODES*FH / TB;      // 32768
  const int gL  = BNODES / 64;         // 2048 lin64 blocks

  // one-kernel CSR build (also inits aliveA)
  k_csr<<<NB, 1024, 0, stream>>>(ei, ea, rowptr, csr_sw, aliveA);

  // ===== Layer 1 =====
  k_degs<0><<<gG, TB, 0, stream>>>(rowptr, csr_sw, aliveA, dinvW, dinvU);
  k_lin1<<<gNH, TB, 0, stream>>>(x, W1, hB);
  k_gather<0><<<gG, TB, 0, stream>>>(rowptr, csr_sw, dinvW, dinvU, hB, b1, Wp1, hA, q);
  k_score<<<gG, TB, 0, stream>>>(rowptr, csr_sw, dinvU, q, bp1, score);
  k_topk<<<NB, 1024, 0, stream>>>(score, aliveA, KK1, tm, aliveB);
  k_sread<<<NB*4, TB, 0, stream>>>(hA, tm, aliveB, pmax, psum);

  // ===== Layer 2 =====
  k_degs<1><<<gG, TB, 0, stream>>>(rowptr, csr_sw, aliveB, dinvW, dinvU);
  k_lin64<<<gL, TB, 0, stream>>>(hA, tm, W2, hB);
  k_gather<1><<<gG, TB, 0, stream>>>(rowptr, csr_sw, dinvW, dinvU, hB, b2, Wp2, hA, q);
  k_score<<<gG, TB, 0, stream>>>(rowptr, csr_sw, dinvU, q, bp2, score);
  k_topk<<<NB, 1024, 0, stream>>>(score, aliveB, KK2, tm, aliveA);
  k_sread<<<NB*4, TB, 0, stream>>>(hA, tm, aliveA, pmax + NB*4*FH, psum + NB*4*FH);

  // ===== Layer 3 =====
  k_degs<2><<<gG, TB, 0, stream>>>(rowptr, csr_sw, aliveA, dinvW, dinvU);
  k_lin64<<<gL, TB, 0, stream>>>(hA, tm, W3, hB);
  k_gather<2><<<gG, TB, 0, stream>>>(rowptr, csr_sw, dinvW, dinvU, hB, b3, Wp3, hA, q);
  k_score<<<gG, TB, 0, stream>>>(rowptr, csr_sw, dinvU, q, bp3, score);
  k_topk<<<NB, 1024, 0, stream>>>(score, aliveA, KK3, tm, aliveB);
  k_sread<<<NB*4, TB, 0, stream>>>(hA, tm, aliveB, pmax + 2*NB*4*FH, psum + 2*NB*4*FH);

  k_mlp<<<NB, FH, 0, stream>>>(pmax, psum, Wl1, bl1, Wl2, bl2, Wl3, bl3, out);
}

// Round 11
// 481.309 us; speedup vs baseline: 2.4599x; 1.0193x over previous
//
#include <hip/hip_runtime.h>
#include <math.h>

#define NB 128            // graphs
#define NN 1024           // nodes per graph
#define BNODES (NB*NN)    // 131072
#define NE 2097152        // edges
#define EPG (NE/NB)       // 16384 edges per graph (edge list is graph-blocked)
#define EPT (EPG/NN)      // 16 edges per thread in k_csr
#define FH 64             // hidden
#define KK1 820
#define KK2 656
#define KK3 525

// ---------------- one-kernel CSR build + layer-1 degrees ----------------
// One 1024-thread block per graph. Edge e of graph b lies in [b*EPG,(b+1)*EPG);
// dst in [b*NN,(b+1)*NN). Count (+weighted degree) via LDS atomics -> LDS scan
// -> LDS-cursor fill into a 128KB dynamic-LDS payload -> coalesced writeout.
__global__ __launch_bounds__(1024) void k_csr(const int* __restrict__ ei,
                                              const float* __restrict__ ea,
                                              int* __restrict__ rowptr,
                                              int2* __restrict__ csr_sw,
                                              int* __restrict__ aliveA,
                                              float* __restrict__ dinvW,
                                              float* __restrict__ dinvU) {
  extern __shared__ int2 lcsr[];          // EPG entries = 128 KB
  __shared__ int cnt[NN];
  __shared__ int cur[NN];
  __shared__ float wsum[NN];
  int b = blockIdx.x, t = threadIdx.x;
  int node = b*NN + t;
  aliveA[node] = 1;
  cnt[t] = 0;
  wsum[t] = 0.f;
  __syncthreads();
  int ebase = b*EPG;
  int se[EPT]; int de[EPT]; float we[EPT];
  #pragma unroll
  for (int i = 0; i < EPT; ++i) {
    int e = ebase + i*NN + t;
    se[i] = ei[e];
    de[i] = ei[NE + e] - b*NN;
    we[i] = ea[e];
    atomicAdd(&cnt[de[i]], 1);
    atomicAdd(&wsum[de[i]], we[i]);
  }
  __syncthreads();
  // in-place Hillis-Steele inclusive scan (read/write separated by barriers)
  int v = cnt[t];
  for (int off = 1; off < NN; off <<= 1) {
    int u = (t >= off) ? cnt[t - off] : 0;
    __syncthreads();
    cnt[t] += u;
    __syncthreads();
  }
  int excl = cnt[t] - v;
  rowptr[node] = ebase + excl;
  cur[t] = excl;
  dinvW[node] = rsqrtf(1.f + wsum[t]);    // layer-1 weighted degree (all alive)
  dinvU[node] = rsqrtf(1.f + (float)v);   // layer-1 unweighted degree
  if (b == NB-1 && t == NN-1) rowptr[BNODES] = NE;
  __syncthreads();
  #pragma unroll
  for (int i = 0; i < EPT; ++i) {
    int pos = atomicAdd(&cur[de[i]], 1);
    lcsr[pos] = make_int2(se[i], __float_as_int(we[i]));
  }
  __syncthreads();
  // coalesced writeout
  float4* dst4 = (float4*)(csr_sw + ebase);
  const float4* src4 = (const float4*)lcsr;
  #pragma unroll
  for (int i = 0; i < EPG/2/NN; ++i)      // EPG int2 = EPG/2 float4 = 8192
    dst4[i*NN + t] = src4[i*NN + t];
}

// ---------------- degrees (layers 2,3): 16-lane group per node ----------------
// MODE 1: w=ea*mask | MODE 2: w=mask. Dead nodes get dinv=0 (self-masking).
template<int MODE>
__global__ void k_degs(const int* __restrict__ rowptr, const int2* __restrict__ csr_sw,
                       const int* __restrict__ alive,
                       float* __restrict__ dinvW, float* __restrict__ dinvU) {
  int t = threadIdx.x;
  int l16 = t & 15;
  int d = blockIdx.x*16 + (t >> 4);
  int r0 = rowptr[d], r1 = rowptr[d+1];
  float sW = 0.f, sU = 0.f;
  for (int base = r0; base < r1; base += 16) {
    if (base + l16 < r1) {
      int2 p = csr_sw[base + l16];
      if (alive[p.x]) { sW += (MODE == 2) ? 1.f : __int_as_float(p.y); sU += 1.f; }
    }
  }
  #pragma unroll
  for (int off = 8; off; off >>= 1) {
    sW += __shfl_xor(sW, off, 16);
    sU += __shfl_xor(sU, off, 16);
  }
  if (l16 == 0) {
    bool dA = (alive[d] != 0);
    dinvW[d] = dA ? rsqrtf(1.f + sW) : 0.f;
    dinvU[d] = dA ? rsqrtf(1.f + sU) : 0.f;
  }
}

// ---------------- layer-1 input transform (2 -> 64) ----------------
__global__ void k_lin1(const float* __restrict__ x, const float* __restrict__ W,
                       float* __restrict__ h) {
  int i = blockIdx.x*256 + threadIdx.x;
  if (i >= BNODES*FH) return;
  int node = i >> 6, f = i & 63;
  h[i] = x[2*node]*W[f] + x[2*node+1]*W[FH + f];
}

// ---------------- fused pool-scale + 64x64 linear ----------------
__global__ void k_lin64(const float* __restrict__ hA, const float* __restrict__ tm,
                        const float* __restrict__ W, float* __restrict__ hB) {
  __shared__ float sX[64][65];
  __shared__ float sW[64*64];
  int t = threadIdx.x;
  for (int i = t; i < 1024; i += 256) ((float4*)sW)[i] = ((const float4*)W)[i];
  int nb = blockIdx.x * 64;
  #pragma unroll
  for (int i = 0; i < 16; ++i) {
    int gidx = (nb << 6) + i*256 + t;
    int node = gidx >> 6, f = gidx & 63;
    sX[node - nb][f] = hA[gidx] * tm[node];
  }
  __syncthreads();
  int node = t >> 2;
  int f0 = (t & 3) * 16;
  float4 a0 = {0,0,0,0}, a1 = a0, a2 = a0, a3 = a0;
  #pragma unroll 4
  for (int k = 0; k < 64; ++k) {
    float xv = sX[node][k];
    const float4 w0 = *(const float4*)&sW[k*64 + f0];
    const float4 w1 = *(const float4*)&sW[k*64 + f0 + 4];
    const float4 w2 = *(const float4*)&sW[k*64 + f0 + 8];
    const float4 w3 = *(const float4*)&sW[k*64 + f0 + 12];
    a0.x = fmaf(xv, w0.x, a0.x); a0.y = fmaf(xv, w0.y, a0.y);
    a0.z = fmaf(xv, w0.z, a0.z); a0.w = fmaf(xv, w0.w, a0.w);
    a1.x = fmaf(xv, w1.x, a1.x); a1.y = fmaf(xv, w1.y, a1.y);
    a1.z = fmaf(xv, w1.z, a1.z); a1.w = fmaf(xv, w1.w, a1.w);
    a2.x = fmaf(xv, w2.x, a2.x); a2.y = fmaf(xv, w2.y, a2.y);
    a2.z = fmaf(xv, w2.z, a2.z); a2.w = fmaf(xv, w2.w, a2.w);
    a3.x = fmaf(xv, w3.x, a3.x); a3.y = fmaf(xv, w3.y, a3.y);
    a3.z = fmaf(xv, w3.z, a3.z); a3.w = fmaf(xv, w3.w, a3.w);
  }
  float4* dst = (float4*)(hB + (size_t)(nb + node)*FH + f0);
  dst[0] = a0; dst[1] = a1; dst[2] = a2; dst[3] = a3;
}

// ---------------- fused GCN gather (4 nodes/wave, float4/lane) ----------------
template<int MODE>
__global__ void k_gather(const int* __restrict__ rowptr, const int2* __restrict__ csr_sw,
                         const float* __restrict__ dinvW, const float* __restrict__ dinvU,
                         const float* __restrict__ hB, const float* __restrict__ b,
                         const float* __restrict__ Wp,
                         float* __restrict__ hA, float* __restrict__ q) {
  int cpx = gridDim.x >> 3;
  int blk = (blockIdx.x & 7) * cpx + (blockIdx.x >> 3);   // XCD swizzle (grid%8==0)
  int t = threadIdx.x;
  int l16 = t & 15;
  int d = blk*16 + (t >> 4);
  const float4* hB4 = (const float4*)hB;

  float dd = dinvW[d];
  float4 hv = hB4[(size_t)d*16 + l16];
  float4 bv = ((const float4*)b)[l16];
  float dd2 = dd*dd;
  float4 acc;
  acc.x = fmaf(dd2, hv.x, bv.x);
  acc.y = fmaf(dd2, hv.y, bv.y);
  acc.z = fmaf(dd2, hv.z, bv.z);
  acc.w = fmaf(dd2, hv.w, bv.w);

  int r0 = rowptr[d], r1 = rowptr[d+1];
  for (int base = r0; base < r1; base += 16) {
    int m = r1 - base;
    int sj = 0; float cj = 0.f;
    if (l16 < m) {
      int2 p = csr_sw[base + l16];
      sj = p.x;
      float w = (MODE == 2) ? 1.f : __int_as_float(p.y);
      cj = dinvW[sj] * w * dd;      // 0 if src or dst dead
    }
    #pragma unroll
    for (int j = 0; j < 16; ++j) {
      int s   = __shfl(sj, j, 16);
      float c = __shfl(cj, j, 16);
      if (c != 0.f) {
        float4 v = hB4[(size_t)s*16 + l16];
        acc.x = fmaf(c, v.x, acc.x);
        acc.y = fmaf(c, v.y, acc.y);
        acc.z = fmaf(c, v.z, acc.z);
        acc.w = fmaf(c, v.w, acc.w);
      }
    }
  }
  acc.x = fmaxf(acc.x, 0.f); acc.y = fmaxf(acc.y, 0.f);
  acc.z = fmaxf(acc.z, 0.f); acc.w = fmaxf(acc.w, 0.f);
  ((float4*)hA)[(size_t)d*16 + l16] = acc;

  float4 wp = ((const float4*)Wp)[l16];
  float dot = acc.x*wp.x + acc.y*wp.y + acc.z*wp.z + acc.w*wp.w;
  #pragma unroll
  for (int off = 8; off; off >>= 1) dot += __shfl_xor(dot, off, 16);
  if (l16 == 0) q[d] = dinvU[d] * dot;    // q = dinvU*(h.Wp); 0 at dead nodes
}

// ---------------- scoring aggregation (q is self-masking) ----------------
__global__ void k_score(const int* __restrict__ rowptr, const int2* __restrict__ csr_sw,
                        const float* __restrict__ dinvU, const float* __restrict__ q,
                        const float* __restrict__ bp, float* __restrict__ score) {
  int t = threadIdx.x;
  int l16 = t & 15;
  int d = blockIdx.x*16 + (t >> 4);
  float du = dinvU[d];
  float sum = 0.f;
  if (du != 0.f) {
    int r0 = rowptr[d], r1 = rowptr[d+1];
    for (int base = r0; base < r1; base += 16)
      if (base + l16 < r1) sum += q[csr_sw[base + l16].x];
  }
  #pragma unroll
  for (int off = 8; off; off >>= 1) sum += __shfl_xor(sum, off, 16);
  if (l16 == 0) score[d] = bp[0] + du*(q[d] + sum);
}

// ---------------- per-graph top-k rank (exact jax.lax.top_k ties) ----------------
__global__ __launch_bounds__(1024) void k_topk(const float* __restrict__ score,
                                               const int* __restrict__ alive, int k,
                                               float* __restrict__ tm,
                                               int* __restrict__ aliveNext) {
  __shared__ float sc[NN];
  int b = blockIdx.x, t = threadIdx.x;
  int node = b*NN + t;
  float raw = score[node];
  float me = alive[node] ? raw : -INFINITY;
  sc[t] = me;
  __syncthreads();
  int rank = 0;
  const float4* sc4 = (const float4*)sc;
  for (int j4 = 0; j4 < NN/4; ++j4) {
    float4 o = sc4[j4];
    int jb = j4*4;
    rank += (o.x > me) || (o.x == me && jb+0 < t);
    rank += (o.y > me) || (o.y == me && jb+1 < t);
    rank += (o.z > me) || (o.z == me && jb+2 < t);
    rank += (o.w > me) || (o.w == me && jb+3 < t);
  }
  int sel = (rank < k) ? 1 : 0;
  aliveNext[node] = sel;
  tm[node] = sel ? tanhf(raw) : 0.f;
}

// ---------------- pool-scale (virtual) + partial readout ----------------
__global__ void k_sread(const float* __restrict__ hA, const float* __restrict__ tm,
                        const int* __restrict__ aliveN,
                        float* __restrict__ pmax, float* __restrict__ psum) {
  __shared__ float rm[4][FH], rs[4][FH];
  int b = blockIdx.x >> 2, p = blockIdx.x & 3;
  int t = threadIdx.x, f = t & 63, r = t >> 6;
  float mx = -INFINITY, sm = 0.f;
  for (int i = 0; i < 64; ++i) {
    int n = p*256 + i*4 + r;
    int node = b*NN + n;
    float v = hA[(size_t)node*FH + f] * tm[node];
    if (aliveN[node]) { mx = fmaxf(mx, v); sm += v; }
  }
  rm[r][f] = mx; rs[r][f] = sm;
  __syncthreads();
  if (t < FH) {
    float m2 = fmaxf(fmaxf(rm[0][t], rm[1][t]), fmaxf(rm[2][t], rm[3][t]));
    float s2 = rs[0][t] + rs[1][t] + rs[2][t] + rs[3][t];
    pmax[(b*4 + p)*FH + t] = m2;
    psum[(b*4 + p)*FH + t] = s2;
  }
}

// ---------------- partial reduce + MLP head + log_softmax ----------------
__global__ void k_mlp(const float* __restrict__ pmax, const float* __restrict__ psum,
                      const float* __restrict__ Wl1, const float* __restrict__ bl1,
                      const float* __restrict__ Wl2, const float* __restrict__ bl2,
                      const float* __restrict__ Wl3, const float* __restrict__ bl3,
                      float* __restrict__ out) {
  __shared__ float sg[2*FH];
  __shared__ float l1[FH];
  __shared__ float l2[FH/2];
  __shared__ float l3[2];
  int b = blockIdx.x, t = threadIdx.x;
  const float kf[3] = {(float)KK1, (float)KK2, (float)KK3};
  float gm = 0.f, gs = 0.f;
  #pragma unroll
  for (int l = 0; l < 3; ++l) {
    const float* pm = pmax + (size_t)l*NB*4*FH + (b*4)*FH;
    const float* ps = psum + (size_t)l*NB*4*FH + (b*4)*FH;
    float mm = -INFINITY, ss = 0.f;
    #pragma unroll
    for (int p = 0; p < 4; ++p) {
      mm = fmaxf(mm, pm[p*FH + t]);
      ss += ps[p*FH + t];
    }
    gm += mm;
    gs += ss / kf[l];
  }
  sg[t] = gm;
  sg[FH + t] = gs;
  __syncthreads();
  float acc = bl1[t];
  #pragma unroll
  for (int k = 0; k < 2*FH; ++k) acc = fmaf(sg[k], Wl1[k*FH + t], acc);
  l1[t] = fmaxf(acc, 0.f);
  __syncthreads();
  if (t < 32) {
    float a2 = bl2[t];
    #pragma unroll
    for (int k = 0; k < FH; ++k) a2 = fmaf(l1[k], Wl2[k*32 + t], a2);
    l2[t] = fmaxf(a2, 0.f);
  }
  __syncthreads();
  if (t < 2) {
    float a3 = bl3[t];
    #pragma unroll
    for (int k = 0; k < 32; ++k) a3 = fmaf(l2[k], Wl3[k*2 + t], a3);
    l3[t] = a3;
  }
  __syncthreads();
  if (t == 0) {
    float m = fmaxf(l3[0], l3[1]);
    float lse = m + logf(expf(l3[0]-m) + expf(l3[1]-m));
    out[b*2+0] = l3[0] - lse;
    out[b*2+1] = l3[1] - lse;
  }
}

extern "C" void kernel_launch(void* const* d_in, const int* in_sizes, int n_in,
                              void* d_out, int out_size, void* d_ws, size_t ws_size,
                              hipStream_t stream) {
  const float* x   = (const float*)d_in[0];
  const float* ea  = (const float*)d_in[1];
  const float* W1  = (const float*)d_in[2];
  const float* b1  = (const float*)d_in[3];
  const float* Wp1 = (const float*)d_in[4];
  const float* bp1 = (const float*)d_in[5];
  const float* W2  = (const float*)d_in[6];
  const float* b2  = (const float*)d_in[7];
  const float* Wp2 = (const float*)d_in[8];
  const float* bp2 = (const float*)d_in[9];
  const float* W3  = (const float*)d_in[10];
  const float* b3  = (const float*)d_in[11];
  const float* Wp3 = (const float*)d_in[12];
  const float* bp3 = (const float*)d_in[13];
  const float* Wl1 = (const float*)d_in[14];
  const float* bl1 = (const float*)d_in[15];
  const float* Wl2 = (const float*)d_in[16];
  const float* bl2 = (const float*)d_in[17];
  const float* Wl3 = (const float*)d_in[18];
  const float* bl3 = (const float*)d_in[19];
  const int*   ei  = (const int*)d_in[20];
  float* out = (float*)d_out;

  // csr_sw first: d_ws base aligned -> int2 naturally aligned.
  int2* csr_sw = (int2*)d_ws;                        // NE
  float* hA    = (float*)(csr_sw + NE);              // BNODES*FH
  float* hB    = hA + (size_t)BNODES*FH;             // BNODES*FH
  float* dinvW = hB + (size_t)BNODES*FH;             // BNODES
  float* dinvU = dinvW + BNODES;                     // BNODES
  float* q     = dinvU + BNODES;                     // BNODES
  float* score = q + BNODES;                         // BNODES
  float* tm    = score + BNODES;                     // BNODES
  float* pmax  = tm + BNODES;                        // 3*NB*4*FH
  float* psum  = pmax + 3*NB*4*FH;                   // 3*NB*4*FH
  int* aliveA  = (int*)(psum + 3*NB*4*FH);           // BNODES
  int* aliveB  = aliveA + BNODES;                    // BNODES
  int* rowptr  = aliveB + BNODES;                    // BNODES+1

  const int TB = 256;
  const int gG  = BNODES / 16;         // 8192 (16 nodes/block)
  const int gNH = BNODES*FH / TB;      // 32768
  const int gL  = BNODES / 64;         // 2048 lin64 blocks

  // one-kernel CSR build (also inits aliveA, computes layer-1 dinvW/dinvU)
  k_csr<<<NB, 1024, EPG*sizeof(int2), stream>>>(ei, ea, rowptr, csr_sw, aliveA,
                                                dinvW, dinvU);

  // ===== Layer 1 =====
  k_lin1<<<gNH, TB, 0, stream>>>(x, W1, hB);
  k_gather<0><<<gG, TB, 0, stream>>>(rowptr, csr_sw, dinvW, dinvU, hB, b1, Wp1, hA, q);
  k_score<<<gG, TB, 0, stream>>>(rowptr, csr_sw, dinvU, q, bp1, score);
  k_topk<<<NB, 1024, 0, stream>>>(score, aliveA, KK1, tm, aliveB);
  k_sread<<<NB*4, TB, 0, stream>>>(hA, tm, aliveB, pmax, psum);

  // ===== Layer 2 =====
  k_degs<1><<<gG, TB, 0, stream>>>(rowptr, csr_sw, aliveB, dinvW, dinvU);
  k_lin64<<<gL, TB, 0, stream>>>(hA, tm, W2, hB);
  k_gather<1><<<gG, TB, 0, stream>>>(rowptr, csr_sw, dinvW, dinvU, hB, b2, Wp2, hA, q);
  k_score<<<gG, TB, 0, stream>>>(rowptr, csr_sw, dinvU, q, bp2, score);
  k_topk<<<NB, 1024, 0, stream>>>(score, aliveB, KK2, tm, aliveA);
  k_sread<<<NB*4, TB, 0, stream>>>(hA, tm, aliveA, pmax + NB*4*FH, psum + NB*4*FH);

  // ===== Layer 3 =====
  k_degs<2><<<gG, TB, 0, stream>>>(rowptr, csr_sw, aliveA, dinvW, dinvU);
  k_lin64<<<gL, TB, 0, stream>>>(hA, tm, W3, hB);
  k_gather<2><<<gG, TB, 0, stream>>>(rowptr, csr_sw, dinvW, dinvU, hB, b3, Wp3, hA, q);
  k_score<<<gG, TB, 0, stream>>>(rowptr, csr_sw, dinvU, q, bp3, score);
  k_topk<<<NB, 1024, 0, stream>>>(score, aliveA, KK3, tm, aliveB);
  k_sread<<<NB*4, TB, 0, stream>>>(hA, tm, aliveB, pmax + 2*NB*4*FH, psum + 2*NB*4*FH);

  k_mlp<<<NB, FH, 0, stream>>>(pmax, psum, Wl1, bl1, Wl2, bl2, Wl3, bl3, out);
}

// Round 13
// 451.983 us; speedup vs baseline: 2.6195x; 1.0649x over previous
//
#include <hip/hip_runtime.h>
#include <math.h>

#define NB 128            // graphs
#define NN 1024           // nodes per graph
#define BNODES (NB*NN)    // 131072
#define NE 2097152        // edges
#define EPG (NE/NB)       // 16384 edges per graph (edge list is graph-blocked)
#define EPT (EPG/NN)      // 16 edges per thread in k_csr
#define FH 64             // hidden
#define KK1 820
#define KK2 656
#define KK3 525

// ---------------- one-kernel CSR build + layer-1 degrees ----------------
__global__ __launch_bounds__(1024) void k_csr(const int* __restrict__ ei,
                                              const float* __restrict__ ea,
                                              int* __restrict__ rowptr,
                                              int2* __restrict__ csr_sw,
                                              int* __restrict__ aliveA,
                                              float* __restrict__ dinvW,
                                              float* __restrict__ dinvU) {
  extern __shared__ int2 lcsr[];          // EPG entries = 128 KB
  __shared__ int cnt[NN];
  __shared__ int cur[NN];
  __shared__ float wsum[NN];
  int b = blockIdx.x, t = threadIdx.x;
  int node = b*NN + t;
  aliveA[node] = 1;
  cnt[t] = 0;
  wsum[t] = 0.f;
  __syncthreads();
  int ebase = b*EPG;
  int se[EPT]; int de[EPT]; float we[EPT];
  #pragma unroll
  for (int i = 0; i < EPT; ++i) {
    int e = ebase + i*NN + t;
    se[i] = ei[e];
    de[i] = ei[NE + e] - b*NN;
    we[i] = ea[e];
    atomicAdd(&cnt[de[i]], 1);
    atomicAdd(&wsum[de[i]], we[i]);
  }
  __syncthreads();
  int v = cnt[t];
  for (int off = 1; off < NN; off <<= 1) {
    int u = (t >= off) ? cnt[t - off] : 0;
    __syncthreads();
    cnt[t] += u;
    __syncthreads();
  }
  int excl = cnt[t] - v;
  rowptr[node] = ebase + excl;
  cur[t] = excl;
  dinvW[node] = rsqrtf(1.f + wsum[t]);
  dinvU[node] = rsqrtf(1.f + (float)v);
  if (b == NB-1 && t == NN-1) rowptr[BNODES] = NE;
  __syncthreads();
  #pragma unroll
  for (int i = 0; i < EPT; ++i) {
    int pos = atomicAdd(&cur[de[i]], 1);
    lcsr[pos] = make_int2(se[i], __float_as_int(we[i]));
  }
  __syncthreads();
  float4* dst4 = (float4*)(csr_sw + ebase);
  const float4* src4 = (const float4*)lcsr;
  #pragma unroll
  for (int i = 0; i < EPG/2/NN; ++i)
    dst4[i*NN + t] = src4[i*NN + t];
}

// ---------------- degrees (layers 2,3): 16-lane group per node ----------------
template<int MODE>
__global__ void k_degs(const int* __restrict__ rowptr, const int2* __restrict__ csr_sw,
                       const int* __restrict__ alive,
                       float* __restrict__ dinvW, float* __restrict__ dinvU) {
  int t = threadIdx.x;
  int l16 = t & 15;
  int d = blockIdx.x*16 + (t >> 4);
  int r0 = rowptr[d], r1 = rowptr[d+1];
  float sW = 0.f, sU = 0.f;
  for (int base = r0; base < r1; base += 16) {
    if (base + l16 < r1) {
      int2 p = csr_sw[base + l16];
      if (alive[p.x]) { sW += (MODE == 2) ? 1.f : __int_as_float(p.y); sU += 1.f; }
    }
  }
  #pragma unroll
  for (int off = 8; off; off >>= 1) {
    sW += __shfl_xor(sW, off, 16);
    sU += __shfl_xor(sU, off, 16);
  }
  if (l16 == 0) {
    bool dA = (alive[d] != 0);
    dinvW[d] = dA ? rsqrtf(1.f + sW) : 0.f;
    dinvU[d] = dA ? rsqrtf(1.f + sU) : 0.f;
  }
}

// ---------------- layer-1 input transform (2 -> 64) ----------------
__global__ void k_lin1(const float* __restrict__ x, const float* __restrict__ W,
                       float* __restrict__ h) {
  int i = blockIdx.x*256 + threadIdx.x;
  if (i >= BNODES*FH) return;
  int node = i >> 6, f = i & 63;
  h[i] = x[2*node]*W[f] + x[2*node+1]*W[FH + f];
}

// ---------------- fused pool-scale + 64x64 linear ----------------
__global__ void k_lin64(const float* __restrict__ hA, const float* __restrict__ tm,
                        const float* __restrict__ W, float* __restrict__ hB) {
  __shared__ float sX[64][65];
  __shared__ float sW[64*64];
  int t = threadIdx.x;
  for (int i = t; i < 1024; i += 256) ((float4*)sW)[i] = ((const float4*)W)[i];
  int nb = blockIdx.x * 64;
  #pragma unroll
  for (int i = 0; i < 16; ++i) {
    int gidx = (nb << 6) + i*256 + t;
    int node = gidx >> 6, f = gidx & 63;
    sX[node - nb][f] = hA[gidx] * tm[node];
  }
  __syncthreads();
  int node = t >> 2;
  int f0 = (t & 3) * 16;
  float4 a0 = {0,0,0,0}, a1 = a0, a2 = a0, a3 = a0;
  #pragma unroll 4
  for (int k = 0; k < 64; ++k) {
    float xv = sX[node][k];
    const float4 w0 = *(const float4*)&sW[k*64 + f0];
    const float4 w1 = *(const float4*)&sW[k*64 + f0 + 4];
    const float4 w2 = *(const float4*)&sW[k*64 + f0 + 8];
    const float4 w3 = *(const float4*)&sW[k*64 + f0 + 12];
    a0.x = fmaf(xv, w0.x, a0.x); a0.y = fmaf(xv, w0.y, a0.y);
    a0.z = fmaf(xv, w0.z, a0.z); a0.w = fmaf(xv, w0.w, a0.w);
    a1.x = fmaf(xv, w1.x, a1.x); a1.y = fmaf(xv, w1.y, a1.y);
    a1.z = fmaf(xv, w1.z, a1.z); a1.w = fmaf(xv, w1.w, a1.w);
    a2.x = fmaf(xv, w2.x, a2.x); a2.y = fmaf(xv, w2.y, a2.y);
    a2.z = fmaf(xv, w2.z, a2.z); a2.w = fmaf(xv, w2.w, a2.w);
    a3.x = fmaf(xv, w3.x, a3.x); a3.y = fmaf(xv, w3.y, a3.y);
    a3.z = fmaf(xv, w3.z, a3.z); a3.w = fmaf(xv, w3.w, a3.w);
  }
  float4* dst = (float4*)(hB + (size_t)(nb + node)*FH + f0);
  dst[0] = a0; dst[1] = a1; dst[2] = a2; dst[3] = a3;
}

// ---------------- fused GCN gather (4 nodes/wave, float4/lane) ----------------
// Unconditional fma: c==0 edges (dead endpoints) contribute exactly 0 —
// removes intra-wave divergence, lets the compiler batch the 16 loads.
template<int MODE>
__global__ void k_gather(const int* __restrict__ rowptr, const int2* __restrict__ csr_sw,
                         const float* __restrict__ dinvW, const float* __restrict__ dinvU,
                         const float* __restrict__ hB, const float* __restrict__ b,
                         const float* __restrict__ Wp,
                         float* __restrict__ hA, float* __restrict__ q) {
  int cpx = gridDim.x >> 3;
  int blk = (blockIdx.x & 7) * cpx + (blockIdx.x >> 3);   // XCD swizzle (grid%8==0)
  int t = threadIdx.x;
  int l16 = t & 15;
  int d = blk*16 + (t >> 4);
  const float4* hB4 = (const float4*)hB;

  float dd = dinvW[d];
  float4 hv = hB4[(size_t)d*16 + l16];
  float4 bv = ((const float4*)b)[l16];
  float dd2 = dd*dd;
  float4 acc;
  acc.x = fmaf(dd2, hv.x, bv.x);
  acc.y = fmaf(dd2, hv.y, bv.y);
  acc.z = fmaf(dd2, hv.z, bv.z);
  acc.w = fmaf(dd2, hv.w, bv.w);

  int r0 = rowptr[d], r1 = rowptr[d+1];
  for (int base = r0; base < r1; base += 16) {
    int m = r1 - base;
    int sj = 0; float cj = 0.f;
    if (l16 < m) {
      int2 p = csr_sw[base + l16];
      sj = p.x;
      float w = (MODE == 2) ? 1.f : __int_as_float(p.y);
      cj = dinvW[sj] * w * dd;      // 0 if src or dst dead (or lane >= m)
    }
    #pragma unroll
    for (int j = 0; j < 16; ++j) {
      int s   = __shfl(sj, j, 16);
      float c = __shfl(cj, j, 16);
      float4 v = hB4[(size_t)s*16 + l16];
      acc.x = fmaf(c, v.x, acc.x);
      acc.y = fmaf(c, v.y, acc.y);
      acc.z = fmaf(c, v.z, acc.z);
      acc.w = fmaf(c, v.w, acc.w);
    }
  }
  acc.x = fmaxf(acc.x, 0.f); acc.y = fmaxf(acc.y, 0.f);
  acc.z = fmaxf(acc.z, 0.f); acc.w = fmaxf(acc.w, 0.f);
  ((float4*)hA)[(size_t)d*16 + l16] = acc;

  float4 wp = ((const float4*)Wp)[l16];
  float dot = acc.x*wp.x + acc.y*wp.y + acc.z*wp.z + acc.w*wp.w;
  #pragma unroll
  for (int off = 8; off; off >>= 1) dot += __shfl_xor(dot, off, 16);
  if (l16 == 0) q[d] = dinvU[d] * dot;    // q = dinvU*(h.Wp); 0 at dead nodes
}

// ---------------- scoring aggregation (q is self-masking) ----------------
__global__ void k_score(const int* __restrict__ rowptr, const int2* __restrict__ csr_sw,
                        const float* __restrict__ dinvU, const float* __restrict__ q,
                        const float* __restrict__ bp, float* __restrict__ score) {
  int t = threadIdx.x;
  int l16 = t & 15;
  int d = blockIdx.x*16 + (t >> 4);
  float du = dinvU[d];
  float sum = 0.f;
  if (du != 0.f) {
    int r0 = rowptr[d], r1 = rowptr[d+1];
    for (int base = r0; base < r1; base += 16)
      if (base + l16 < r1) sum += q[csr_sw[base + l16].x];
  }
  #pragma unroll
  for (int off = 8; off; off >>= 1) sum += __shfl_xor(sum, off, 16);
  if (l16 == 0) score[d] = bp[0] + du*(q[d] + sum);
}

// ---------------- top-k rank: 4 blocks/graph, 256 threads, thread = node ----------------
__global__ void k_topk(const float* __restrict__ score,
                       const int* __restrict__ alive, int k,
                       float* __restrict__ tm, int* __restrict__ aliveNext) {
  __shared__ float sc[NN];
  int b = blockIdx.x >> 2, p = blockIdx.x & 3;
  int t = threadIdx.x;
  int gbase = b*NN;
  // stage all 1024 masked scores (4 loads per thread)
  #pragma unroll
  for (int i = 0; i < 4; ++i) {
    int n = i*256 + t;
    sc[n] = alive[gbase + n] ? score[gbase + n] : -INFINITY;
  }
  __syncthreads();
  int n = p*256 + t;              // this thread's node
  int node = gbase + n;
  float me = sc[n];
  float raw = score[node];
  int rank = 0;
  const float4* sc4 = (const float4*)sc;
  for (int j4 = 0; j4 < NN/4; ++j4) {
    float4 o = sc4[j4];
    int jb = j4*4;
    rank += (o.x > me) || (o.x == me && jb+0 < n);
    rank += (o.y > me) || (o.y == me && jb+1 < n);
    rank += (o.z > me) || (o.z == me && jb+2 < n);
    rank += (o.w > me) || (o.w == me && jb+3 < n);
  }
  int sel = (rank < k) ? 1 : 0;
  aliveNext[node] = sel;
  tm[node] = sel ? tanhf(raw) : 0.f;
}

// ---------------- pool-scale (virtual) + partial readout ----------------
__global__ void k_sread(const float* __restrict__ hA, const float* __restrict__ tm,
                        const int* __restrict__ aliveN,
                        float* __restrict__ pmax, float* __restrict__ psum) {
  __shared__ float rm[4][FH], rs[4][FH];
  int b = blockIdx.x >> 2, p = blockIdx.x & 3;
  int t = threadIdx.x, f = t & 63, r = t >> 6;
  float mx = -INFINITY, sm = 0.f;
  for (int i = 0; i < 64; ++i) {
    int n = p*256 + i*4 + r;
    int node = b*NN + n;
    float v = hA[(size_t)node*FH + f] * tm[node];
    if (aliveN[node]) { mx = fmaxf(mx, v); sm += v; }
  }
  rm[r][f] = mx; rs[r][f] = sm;
  __syncthreads();
  if (t < FH) {
    float m2 = fmaxf(fmaxf(rm[0][t], rm[1][t]), fmaxf(rm[2][t], rm[3][t]));
    float s2 = rs[0][t] + rs[1][t] + rs[2][t] + rs[3][t];
    pmax[(b*4 + p)*FH + t] = m2;
    psum[(b*4 + p)*FH + t] = s2;
  }
}

// ---------------- partial reduce + MLP head + log_softmax ----------------
__global__ void k_mlp(const float* __restrict__ pmax, const float* __restrict__ psum,
                      const float* __restrict__ Wl1, const float* __restrict__ bl1,
                      const float* __restrict__ Wl2, const float* __restrict__ bl2,
                      const float* __restrict__ Wl3, const float* __restrict__ bl3,
                      float* __restrict__ out) {
  __shared__ float sg[2*FH];
  __shared__ float l1[FH];
  __shared__ float l2[FH/2];
  __shared__ float l3[2];
  int b = blockIdx.x, t = threadIdx.x;
  const float kf[3] = {(float)KK1, (float)KK2, (float)KK3};
  float gm = 0.f, gs = 0.f;
  #pragma unroll
  for (int l = 0; l < 3; ++l) {
    const float* pm = pmax + (size_t)l*NB*4*FH + (b*4)*FH;
    const float* ps = psum + (size_t)l*NB*4*FH + (b*4)*FH;
    float mm = -INFINITY, ss = 0.f;
    #pragma unroll
    for (int p = 0; p < 4; ++p) {
      mm = fmaxf(mm, pm[p*FH + t]);
      ss += ps[p*FH + t];
    }
    gm += mm;
    gs += ss / kf[l];
  }
  sg[t] = gm;
  sg[FH + t] = gs;
  __syncthreads();
  float acc = bl1[t];
  #pragma unroll
  for (int k = 0; k < 2*FH; ++k) acc = fmaf(sg[k], Wl1[k*FH + t], acc);
  l1[t] = fmaxf(acc, 0.f);
  __syncthreads();
  if (t < 32) {
    float a2 = bl2[t];
    #pragma unroll
    for (int k = 0; k < FH; ++k) a2 = fmaf(l1[k], Wl2[k*32 + t], a2);
    l2[t] = fmaxf(a2, 0.f);
  }
  __syncthreads();
  if (t < 2) {
    float a3 = bl3[t];
    #pragma unroll
    for (int k = 0; k < 32; ++k) a3 = fmaf(l2[k], Wl3[k*2 + t], a3);
    l3[t] = a3;
  }
  __syncthreads();
  if (t == 0) {
    float m = fmaxf(l3[0], l3[1]);
    float lse = m + logf(expf(l3[0]-m) + expf(l3[1]-m));
    out[b*2+0] = l3[0] - lse;
    out[b*2+1] = l3[1] - lse;
  }
}

extern "C" void kernel_launch(void* const* d_in, const int* in_sizes, int n_in,
                              void* d_out, int out_size, void* d_ws, size_t ws_size,
                              hipStream_t stream) {
  const float* x   = (const float*)d_in[0];
  const float* ea  = (const float*)d_in[1];
  const float* W1  = (const float*)d_in[2];
  const float* b1  = (const float*)d_in[3];
  const float* Wp1 = (const float*)d_in[4];
  const float* bp1 = (const float*)d_in[5];
  const float* W2  = (const float*)d_in[6];
  const float* b2  = (const float*)d_in[7];
  const float* Wp2 = (const float*)d_in[8];
  const float* bp2 = (const float*)d_in[9];
  const float* W3  = (const float*)d_in[10];
  const float* b3  = (const float*)d_in[11];
  const float* Wp3 = (const float*)d_in[12];
  const float* bp3 = (const float*)d_in[13];
  const float* Wl1 = (const float*)d_in[14];
  const float* bl1 = (const float*)d_in[15];
  const float* Wl2 = (const float*)d_in[16];
  const float* bl2 = (const float*)d_in[17];
  const float* Wl3 = (const float*)d_in[18];
  const float* bl3 = (const float*)d_in[19];
  const int*   ei  = (const int*)d_in[20];
  float* out = (float*)d_out;

  int2* csr_sw = (int2*)d_ws;                        // NE
  float* hA    = (float*)(csr_sw + NE);              // BNODES*FH
  float* hB    = hA + (size_t)BNODES*FH;             // BNODES*FH
  float* dinvW = hB + (size_t)BNODES*FH;             // BNODES
  float* dinvU = dinvW + BNODES;                     // BNODES
  float* q     = dinvU + BNODES;                     // BNODES
  float* score = q + BNODES;                         // BNODES
  float* tm    = score + BNODES;                     // BNODES
  float* pmax  = tm + BNODES;                        // 3*NB*4*FH
  float* psum  = pmax + 3*NB*4*FH;                   // 3*NB*4*FH
  int* aliveA  = (int*)(psum + 3*NB*4*FH);           // BNODES
  int* aliveB  = aliveA + BNODES;                    // BNODES
  int* rowptr  = aliveB + BNODES;                    // BNODES+1

  const int TB = 256;
  const int gG  = BNODES / 16;         // 8192 (16 nodes/block)
  const int gNH = BNODES*FH / TB;      // 32768
  const int gL  = BNODES / 64;         // 2048 lin64 blocks

  k_csr<<<NB, 1024, EPG*sizeof(int2), stream>>>(ei, ea, rowptr, csr_sw, aliveA,
                                                dinvW, dinvU);

  // ===== Layer 1 =====
  k_lin1<<<gNH, TB, 0, stream>>>(x, W1, hB);
  k_gather<0><<<gG, TB, 0, stream>>>(rowptr, csr_sw, dinvW, dinvU, hB, b1, Wp1, hA, q);
  k_score<<<gG, TB, 0, stream>>>(rowptr, csr_sw, dinvU, q, bp1, score);
  k_topk<<<NB*4, TB, 0, stream>>>(score, aliveA, KK1, tm, aliveB);
  k_sread<<<NB*4, TB, 0, stream>>>(hA, tm, aliveB, pmax, psum);

  // ===== Layer 2 =====
  k_degs<1><<<gG, TB, 0, stream>>>(rowptr, csr_sw, aliveB, dinvW, dinvU);
  k_lin64<<<gL, TB, 0, stream>>>(hA, tm, W2, hB);
  k_gather<1><<<gG, TB, 0, stream>>>(rowptr, csr_sw, dinvW, dinvU, hB, b2, Wp2, hA, q);
  k_score<<<gG, TB, 0, stream>>>(rowptr, csr_sw, dinvU, q, bp2, score);
  k_topk<<<NB*4, TB, 0, stream>>>(score, aliveB, KK2, tm, aliveA);
  k_sread<<<NB*4, TB, 0, stream>>>(hA, tm, aliveA, pmax + NB*4*FH, psum + NB*4*FH);

  // ===== Layer 3 =====
  k_degs<2><<<gG, TB, 0, stream>>>(rowptr, csr_sw, aliveA, dinvW, dinvU);
  k_lin64<<<gL, TB, 0, stream>>>(hA, tm, W3, hB);
  k_gather<2><<<gG, TB, 0, stream>>>(rowptr, csr_sw, dinvW, dinvU, hB, b3, Wp3, hA, q);
  k_score<<<gG, TB, 0, stream>>>(rowptr, csr_sw, dinvU, q, bp3, score);
  k_topk<<<NB*4, TB, 0, stream>>>(score, aliveA, KK3, tm, aliveB);
  k_sread<<<NB*4, TB, 0, stream>>>(hA, tm, aliveB, pmax + 2*NB*4*FH, psum + 2*NB*4*FH);

  k_mlp<<<NB, FH, 0, stream>>>(pmax, psum, Wl1, bl1, Wl2, bl2, Wl3, bl3, out);
}

// Round 14
// 451.885 us; speedup vs baseline: 2.6200x; 1.0002x over previous
//
#include <hip/hip_runtime.h>
#include <math.h>

#define NB 128            // graphs
#define NN 1024           // nodes per graph
#define BNODES (NB*NN)    // 131072
#define NE 2097152        // edges
#define EPG (NE/NB)       // 16384 edges per graph (edge list is graph-blocked)
#define EPT (EPG/NN)      // 16 edges per thread in k_csr
#define FH 64             // hidden
#define KK1 820
#define KK2 656
#define KK3 525

// ---------------- one-kernel CSR build + layer-1 degrees ----------------
__global__ __launch_bounds__(1024) void k_csr(const int* __restrict__ ei,
                                              const float* __restrict__ ea,
                                              int* __restrict__ rowptr,
                                              int2* __restrict__ csr_sw,
                                              int* __restrict__ aliveA,
                                              float* __restrict__ dinvW,
                                              float* __restrict__ dinvU) {
  extern __shared__ int2 lcsr[];          // EPG entries = 128 KB
  __shared__ int cnt[NN];
  __shared__ int cur[NN];
  __shared__ float wsum[NN];
  int b = blockIdx.x, t = threadIdx.x;
  int node = b*NN + t;
  aliveA[node] = 1;
  cnt[t] = 0;
  wsum[t] = 0.f;
  __syncthreads();
  int ebase = b*EPG;
  int se[EPT]; int de[EPT]; float we[EPT];
  #pragma unroll
  for (int i = 0; i < EPT; ++i) {
    int e = ebase + i*NN + t;
    se[i] = ei[e];
    de[i] = ei[NE + e] - b*NN;
    we[i] = ea[e];
    atomicAdd(&cnt[de[i]], 1);
    atomicAdd(&wsum[de[i]], we[i]);
  }
  __syncthreads();
  int v = cnt[t];
  for (int off = 1; off < NN; off <<= 1) {
    int u = (t >= off) ? cnt[t - off] : 0;
    __syncthreads();
    cnt[t] += u;
    __syncthreads();
  }
  int excl = cnt[t] - v;
  rowptr[node] = ebase + excl;
  cur[t] = excl;
  dinvW[node] = rsqrtf(1.f + wsum[t]);
  dinvU[node] = rsqrtf(1.f + (float)v);
  if (b == NB-1 && t == NN-1) rowptr[BNODES] = NE;
  __syncthreads();
  #pragma unroll
  for (int i = 0; i < EPT; ++i) {
    int pos = atomicAdd(&cur[de[i]], 1);
    lcsr[pos] = make_int2(se[i], __float_as_int(we[i]));
  }
  __syncthreads();
  float4* dst4 = (float4*)(csr_sw + ebase);
  const float4* src4 = (const float4*)lcsr;
  #pragma unroll
  for (int i = 0; i < EPG/2/NN; ++i)
    dst4[i*NN + t] = src4[i*NN + t];
}

// ---------------- degrees (layers 2,3): 16-lane group per node ----------------
template<int MODE>
__global__ void k_degs(const int* __restrict__ rowptr, const int2* __restrict__ csr_sw,
                       const int* __restrict__ alive,
                       float* __restrict__ dinvW, float* __restrict__ dinvU) {
  int t = threadIdx.x;
  int l16 = t & 15;
  int d = blockIdx.x*16 + (t >> 4);
  int r0 = rowptr[d], r1 = rowptr[d+1];
  float sW = 0.f, sU = 0.f;
  for (int base = r0; base < r1; base += 16) {
    if (base + l16 < r1) {
      int2 p = csr_sw[base + l16];
      if (alive[p.x]) { sW += (MODE == 2) ? 1.f : __int_as_float(p.y); sU += 1.f; }
    }
  }
  #pragma unroll
  for (int off = 8; off; off >>= 1) {
    sW += __shfl_xor(sW, off, 16);
    sU += __shfl_xor(sU, off, 16);
  }
  if (l16 == 0) {
    bool dA = (alive[d] != 0);
    dinvW[d] = dA ? rsqrtf(1.f + sW) : 0.f;
    dinvU[d] = dA ? rsqrtf(1.f + sU) : 0.f;
  }
}

// ---------------- layer-1 input transform (2 -> 64) ----------------
__global__ void k_lin1(const float* __restrict__ x, const float* __restrict__ W,
                       float* __restrict__ h) {
  int i = blockIdx.x*256 + threadIdx.x;
  if (i >= BNODES*FH) return;
  int node = i >> 6, f = i & 63;
  h[i] = x[2*node]*W[f] + x[2*node+1]*W[FH + f];
}

// ---------------- fused pool-scale + 64x64 linear ----------------
__global__ void k_lin64(const float* __restrict__ hA, const float* __restrict__ tm,
                        const float* __restrict__ W, float* __restrict__ hB) {
  __shared__ float sX[64][65];
  __shared__ float sW[64*64];
  int t = threadIdx.x;
  for (int i = t; i < 1024; i += 256) ((float4*)sW)[i] = ((const float4*)W)[i];
  int nb = blockIdx.x * 64;
  #pragma unroll
  for (int i = 0; i < 16; ++i) {
    int gidx = (nb << 6) + i*256 + t;
    int node = gidx >> 6, f = gidx & 63;
    sX[node - nb][f] = hA[gidx] * tm[node];
  }
  __syncthreads();
  int node = t >> 2;
  int f0 = (t & 3) * 16;
  float4 a0 = {0,0,0,0}, a1 = a0, a2 = a0, a3 = a0;
  #pragma unroll 4
  for (int k = 0; k < 64; ++k) {
    float xv = sX[node][k];
    const float4 w0 = *(const float4*)&sW[k*64 + f0];
    const float4 w1 = *(const float4*)&sW[k*64 + f0 + 4];
    const float4 w2 = *(const float4*)&sW[k*64 + f0 + 8];
    const float4 w3 = *(const float4*)&sW[k*64 + f0 + 12];
    a0.x = fmaf(xv, w0.x, a0.x); a0.y = fmaf(xv, w0.y, a0.y);
    a0.z = fmaf(xv, w0.z, a0.z); a0.w = fmaf(xv, w0.w, a0.w);
    a1.x = fmaf(xv, w1.x, a1.x); a1.y = fmaf(xv, w1.y, a1.y);
    a1.z = fmaf(xv, w1.z, a1.z); a1.w = fmaf(xv, w1.w, a1.w);
    a2.x = fmaf(xv, w2.x, a2.x); a2.y = fmaf(xv, w2.y, a2.y);
    a2.z = fmaf(xv, w2.z, a2.z); a2.w = fmaf(xv, w2.w, a2.w);
    a3.x = fmaf(xv, w3.x, a3.x); a3.y = fmaf(xv, w3.y, a3.y);
    a3.z = fmaf(xv, w3.z, a3.z); a3.w = fmaf(xv, w3.w, a3.w);
  }
  float4* dst = (float4*)(hB + (size_t)(nb + node)*FH + f0);
  dst[0] = a0; dst[1] = a1; dst[2] = a2; dst[3] = a3;
}

// ---------------- fused GCN gather (4 nodes/wave, float4/lane) ----------------
// Two-phase inner loop: batch all 16 row-loads into v[16] (static-indexed,
// stays in registers), then the fma chain. __launch_bounds__(256,4) raises
// the VGPR cap to 128 so all 16 loads stay in flight (MLP fix).
template<int MODE>
__global__ __launch_bounds__(256, 4) void k_gather(
                         const int* __restrict__ rowptr, const int2* __restrict__ csr_sw,
                         const float* __restrict__ dinvW, const float* __restrict__ dinvU,
                         const float* __restrict__ hB, const float* __restrict__ b,
                         const float* __restrict__ Wp,
                         float* __restrict__ hA, float* __restrict__ q) {
  int cpx = gridDim.x >> 3;
  int blk = (blockIdx.x & 7) * cpx + (blockIdx.x >> 3);   // XCD swizzle (grid%8==0)
  int t = threadIdx.x;
  int l16 = t & 15;
  int d = blk*16 + (t >> 4);
  const float4* hB4 = (const float4*)hB;

  float dd = dinvW[d];
  float4 hv = hB4[(size_t)d*16 + l16];
  float4 bv = ((const float4*)b)[l16];
  float dd2 = dd*dd;
  float4 acc;
  acc.x = fmaf(dd2, hv.x, bv.x);
  acc.y = fmaf(dd2, hv.y, bv.y);
  acc.z = fmaf(dd2, hv.z, bv.z);
  acc.w = fmaf(dd2, hv.w, bv.w);

  int r0 = rowptr[d], r1 = rowptr[d+1];
  for (int base = r0; base < r1; base += 16) {
    int m = r1 - base;
    int sj = 0; float cj = 0.f;
    if (l16 < m) {
      int2 p = csr_sw[base + l16];
      sj = p.x;
      float w = (MODE == 2) ? 1.f : __int_as_float(p.y);
      cj = dinvW[sj] * w * dd;      // 0 if src or dst dead (or lane >= m)
    }
    // phase 1: issue all 16 independent row loads
    float4 v[16];
    #pragma unroll
    for (int j = 0; j < 16; ++j) {
      int s = __shfl(sj, j, 16);
      v[j] = hB4[(size_t)s*16 + l16];
    }
    // phase 2: accumulate
    #pragma unroll
    for (int j = 0; j < 16; ++j) {
      float c = __shfl(cj, j, 16);
      acc.x = fmaf(c, v[j].x, acc.x);
      acc.y = fmaf(c, v[j].y, acc.y);
      acc.z = fmaf(c, v[j].z, acc.z);
      acc.w = fmaf(c, v[j].w, acc.w);
    }
  }
  acc.x = fmaxf(acc.x, 0.f); acc.y = fmaxf(acc.y, 0.f);
  acc.z = fmaxf(acc.z, 0.f); acc.w = fmaxf(acc.w, 0.f);
  ((float4*)hA)[(size_t)d*16 + l16] = acc;

  float4 wp = ((const float4*)Wp)[l16];
  float dot = acc.x*wp.x + acc.y*wp.y + acc.z*wp.z + acc.w*wp.w;
  #pragma unroll
  for (int off = 8; off; off >>= 1) dot += __shfl_xor(dot, off, 16);
  if (l16 == 0) q[d] = dinvU[d] * dot;    // q = dinvU*(h.Wp); 0 at dead nodes
}

// ---------------- scoring aggregation (q is self-masking) ----------------
__global__ void k_score(const int* __restrict__ rowptr, const int2* __restrict__ csr_sw,
                        const float* __restrict__ dinvU, const float* __restrict__ q,
                        const float* __restrict__ bp, float* __restrict__ score) {
  int t = threadIdx.x;
  int l16 = t & 15;
  int d = blockIdx.x*16 + (t >> 4);
  float du = dinvU[d];
  float sum = 0.f;
  if (du != 0.f) {
    int r0 = rowptr[d], r1 = rowptr[d+1];
    for (int base = r0; base < r1; base += 16)
      if (base + l16 < r1) sum += q[csr_sw[base + l16].x];
  }
  #pragma unroll
  for (int off = 8; off; off >>= 1) sum += __shfl_xor(sum, off, 16);
  if (l16 == 0) score[d] = bp[0] + du*(q[d] + sum);
}

// ---------------- top-k rank: 4 blocks/graph, 256 threads, thread = node ----------------
__global__ void k_topk(const float* __restrict__ score,
                       const int* __restrict__ alive, int k,
                       float* __restrict__ tm, int* __restrict__ aliveNext) {
  __shared__ float sc[NN];
  int b = blockIdx.x >> 2, p = blockIdx.x & 3;
  int t = threadIdx.x;
  int gbase = b*NN;
  #pragma unroll
  for (int i = 0; i < 4; ++i) {
    int n = i*256 + t;
    sc[n] = alive[gbase + n] ? score[gbase + n] : -INFINITY;
  }
  __syncthreads();
  int n = p*256 + t;              // this thread's node
  int node = gbase + n;
  float me = sc[n];
  float raw = score[node];
  int rank = 0;
  const float4* sc4 = (const float4*)sc;
  for (int j4 = 0; j4 < NN/4; ++j4) {
    float4 o = sc4[j4];
    int jb = j4*4;
    rank += (o.x > me) || (o.x == me && jb+0 < n);
    rank += (o.y > me) || (o.y == me && jb+1 < n);
    rank += (o.z > me) || (o.z == me && jb+2 < n);
    rank += (o.w > me) || (o.w == me && jb+3 < n);
  }
  int sel = (rank < k) ? 1 : 0;
  aliveNext[node] = sel;
  tm[node] = sel ? tanhf(raw) : 0.f;
}

// ---------------- pool-scale (virtual) + partial readout ----------------
__global__ void k_sread(const float* __restrict__ hA, const float* __restrict__ tm,
                        const int* __restrict__ aliveN,
                        float* __restrict__ pmax, float* __restrict__ psum) {
  __shared__ float rm[4][FH], rs[4][FH];
  int b = blockIdx.x >> 2, p = blockIdx.x & 3;
  int t = threadIdx.x, f = t & 63, r = t >> 6;
  float mx = -INFINITY, sm = 0.f;
  for (int i = 0; i < 64; ++i) {
    int n = p*256 + i*4 + r;
    int node = b*NN + n;
    float v = hA[(size_t)node*FH + f] * tm[node];
    if (aliveN[node]) { mx = fmaxf(mx, v); sm += v; }
  }
  rm[r][f] = mx; rs[r][f] = sm;
  __syncthreads();
  if (t < FH) {
    float m2 = fmaxf(fmaxf(rm[0][t], rm[1][t]), fmaxf(rm[2][t], rm[3][t]));
    float s2 = rs[0][t] + rs[1][t] + rs[2][t] + rs[3][t];
    pmax[(b*4 + p)*FH + t] = m2;
    psum[(b*4 + p)*FH + t] = s2;
  }
}

// ---------------- partial reduce + MLP head + log_softmax ----------------
__global__ void k_mlp(const float* __restrict__ pmax, const float* __restrict__ psum,
                      const float* __restrict__ Wl1, const float* __restrict__ bl1,
                      const float* __restrict__ Wl2, const float* __restrict__ bl2,
                      const float* __restrict__ Wl3, const float* __restrict__ bl3,
                      float* __restrict__ out) {
  __shared__ float sg[2*FH];
  __shared__ float l1[FH];
  __shared__ float l2[FH/2];
  __shared__ float l3[2];
  int b = blockIdx.x, t = threadIdx.x;
  const float kf[3] = {(float)KK1, (float)KK2, (float)KK3};
  float gm = 0.f, gs = 0.f;
  #pragma unroll
  for (int l = 0; l < 3; ++l) {
    const float* pm = pmax + (size_t)l*NB*4*FH + (b*4)*FH;
    const float* ps = psum + (size_t)l*NB*4*FH + (b*4)*FH;
    float mm = -INFINITY, ss = 0.f;
    #pragma unroll
    for (int p = 0; p < 4; ++p) {
      mm = fmaxf(mm, pm[p*FH + t]);
      ss += ps[p*FH + t];
    }
    gm += mm;
    gs += ss / kf[l];
  }
  sg[t] = gm;
  sg[FH + t] = gs;
  __syncthreads();
  float acc = bl1[t];
  #pragma unroll
  for (int k = 0; k < 2*FH; ++k) acc = fmaf(sg[k], Wl1[k*FH + t], acc);
  l1[t] = fmaxf(acc, 0.f);
  __syncthreads();
  if (t < 32) {
    float a2 = bl2[t];
    #pragma unroll
    for (int k = 0; k < FH; ++k) a2 = fmaf(l1[k], Wl2[k*32 + t], a2);
    l2[t] = fmaxf(a2, 0.f);
  }
  __syncthreads();
  if (t < 2) {
    float a3 = bl3[t];
    #pragma unroll
    for (int k = 0; k < 32; ++k) a3 = fmaf(l2[k], Wl3[k*2 + t], a3);
    l3[t] = a3;
  }
  __syncthreads();
  if (t == 0) {
    float m = fmaxf(l3[0], l3[1]);
    float lse = m + logf(expf(l3[0]-m) + expf(l3[1]-m));
    out[b*2+0] = l3[0] - lse;
    out[b*2+1] = l3[1] - lse;
  }
}

extern "C" void kernel_launch(void* const* d_in, const int* in_sizes, int n_in,
                              void* d_out, int out_size, void* d_ws, size_t ws_size,
                              hipStream_t stream) {
  const float* x   = (const float*)d_in[0];
  const float* ea  = (const float*)d_in[1];
  const float* W1  = (const float*)d_in[2];
  const float* b1  = (const float*)d_in[3];
  const float* Wp1 = (const float*)d_in[4];
  const float* bp1 = (const float*)d_in[5];
  const float* W2  = (const float*)d_in[6];
  const float* b2  = (const float*)d_in[7];
  const float* Wp2 = (const float*)d_in[8];
  const float* bp2 = (const float*)d_in[9];
  const float* W3  = (const float*)d_in[10];
  const float* b3  = (const float*)d_in[11];
  const float* Wp3 = (const float*)d_in[12];
  const float* bp3 = (const float*)d_in[13];
  const float* Wl1 = (const float*)d_in[14];
  const float* bl1 = (const float*)d_in[15];
  const float* Wl2 = (const float*)d_in[16];
  const float* bl2 = (const float*)d_in[17];
  const float* Wl3 = (const float*)d_in[18];
  const float* bl3 = (const float*)d_in[19];
  const int*   ei  = (const int*)d_in[20];
  float* out = (float*)d_out;

  int2* csr_sw = (int2*)d_ws;                        // NE
  float* hA    = (float*)(csr_sw + NE);              // BNODES*FH
  float* hB    = hA + (size_t)BNODES*FH;             // BNODES*FH
  float* dinvW = hB + (size_t)BNODES*FH;             // BNODES
  float* dinvU = dinvW + BNODES;                     // BNODES
  float* q     = dinvU + BNODES;                     // BNODES
  float* score = q + BNODES;                         // BNODES
  float* tm    = score + BNODES;                     // BNODES
  float* pmax  = tm + BNODES;                        // 3*NB*4*FH
  float* psum  = pmax + 3*NB*4*FH;                   // 3*NB*4*FH
  int* aliveA  = (int*)(psum + 3*NB*4*FH);           // BNODES
  int* aliveB  = aliveA + BNODES;                    // BNODES
  int* rowptr  = aliveB + BNODES;                    // BNODES+1

  const int TB = 256;
  const int gG  = BNODES / 16;         // 8192 (16 nodes/block)
  const int gNH = BNODES*FH / TB;      // 32768
  const int gL  = BNODES / 64;         // 2048 lin64 blocks

  k_csr<<<NB, 1024, EPG*sizeof(int2), stream>>>(ei, ea, rowptr, csr_sw, aliveA,
                                                dinvW, dinvU);

  // ===== Layer 1 =====
  k_lin1<<<gNH, TB, 0, stream>>>(x, W1, hB);
  k_gather<0><<<gG, TB, 0, stream>>>(rowptr, csr_sw, dinvW, dinvU, hB, b1, Wp1, hA, q);
  k_score<<<gG, TB, 0, stream>>>(rowptr, csr_sw, dinvU, q, bp1, score);
  k_topk<<<NB*4, TB, 0, stream>>>(score, aliveA, KK1, tm, aliveB);
  k_sread<<<NB*4, TB, 0, stream>>>(hA, tm, aliveB, pmax, psum);

  // ===== Layer 2 =====
  k_degs<1><<<gG, TB, 0, stream>>>(rowptr, csr_sw, aliveB, dinvW, dinvU);
  k_lin64<<<gL, TB, 0, stream>>>(hA, tm, W2, hB);
  k_gather<1><<<gG, TB, 0, stream>>>(rowptr, csr_sw, dinvW, dinvU, hB, b2, Wp2, hA, q);
  k_score<<<gG, TB, 0, stream>>>(rowptr, csr_sw, dinvU, q, bp2, score);
  k_topk<<<NB*4, TB, 0, stream>>>(score, aliveB, KK2, tm, aliveA);
  k_sread<<<NB*4, TB, 0, stream>>>(hA, tm, aliveA, pmax + NB*4*FH, psum + NB*4*FH);

  // ===== Layer 3 =====
  k_degs<2><<<gG, TB, 0, stream>>>(rowptr, csr_sw, aliveA, dinvW, dinvU);
  k_lin64<<<gL, TB, 0, stream>>>(hA, tm, W3, hB);
  k_gather<2><<<gG, TB, 0, stream>>>(rowptr, csr_sw, dinvW, dinvU, hB, b3, Wp3, hA, q);
  k_score<<<gG, TB, 0, stream>>>(rowptr, csr_sw, dinvU, q, bp3, score);
  k_topk<<<NB*4, TB, 0, stream>>>(score, aliveA, KK3, tm, aliveB);
  k_sread<<<NB*4, TB, 0, stream>>>(hA, tm, aliveB, pmax + 2*NB*4*FH, psum + 2*NB*4*FH);

  k_mlp<<<NB, FH, 0, stream>>>(pmax, psum, Wl1, bl1, Wl2, bl2, Wl3, bl3, out);
}